// Round 12
// baseline (574.899 us; speedup 1.0000x reference)
//
#include <hip/hip_runtime.h>
#include <cstdint>
#include <cstddef>

// Problem constants
#define BN_   16
#define LN_   1024
#define DM_   384
#define DI_   768
#define NS_   16
#define RDT_  24
#define NDBC_ 56
#define NDBCP 64     // padded dbc stride
#define NC_   16
#define LC_   64

typedef unsigned short ushortT;
typedef short bf16x8 __attribute__((ext_vector_type(8)));
typedef float f32x4 __attribute__((ext_vector_type(4)));

typedef __attribute__((address_space(3))) uint32_t lds_u32_t;
typedef __attribute__((address_space(1))) const uint32_t glb_u32_t;

static __device__ __forceinline__ void stage16(const void* g, void* lds) {
    __builtin_amdgcn_global_load_lds(
        (glb_u32_t*)(uintptr_t)g,
        (lds_u32_t*)(uint32_t)(uintptr_t)lds,
        16, 0, 0);
}

// XOR-swizzle helpers for 16B granules in 64B rows (kills 8-way ds_read_b128
// bank conflicts -> free 2-way). Stage: lane l sources global granule
// (l&3)^((l>>3)&3). Read: fragment granule q at row m lives at q^((m>>1)&3).
static __device__ __forceinline__ int stage_sw(int lane) {
    return ((lane & 3) ^ ((lane >> 3) & 3)) * 8;   // ushort offset
}
static __device__ __forceinline__ int read_sw(int lane) {
    return (((lane >> 4) ^ (((lane & 15) >> 1) & 3)) * 8);  // ushort offset
}

static __device__ __forceinline__ float silu_f(float x) {
    return x / (1.0f + __expf(-x));
}
// fast softplus: ln(1+e^s) = max(s,0) + ln(1+e^-|s|)
static __device__ __forceinline__ float softplus_f(float s) {
    return fmaxf(s, 0.0f) + __logf(1.0f + __expf(-fabsf(s)));
}
static __device__ __forceinline__ ushortT f2bf(float f) {
    union { float f; uint32_t u; } v; v.f = f;
    uint32_t u = v.u;
    uint32_t r = u + 0x7fffu + ((u >> 16) & 1u);
    return (ushortT)(r >> 16);
}
static __device__ __forceinline__ float bf2f(ushortT b) {
    union { uint32_t u; float f; } v; v.u = ((uint32_t)b) << 16;
    return v.f;
}

// ---------------------------------------------------------------------------
// Weight conversions: in_proj/out_proj fp32->bf16; xproj bf16 padded to 64
// rows; dt_w bf16 padded to 32 cols (24..31 zero).
// ---------------------------------------------------------------------------
__global__ __launch_bounds__(256) void wconv_kernel(
    const float* __restrict__ w1, int n1, const float* __restrict__ w2, int n2,
    const float* __restrict__ xwf, const float* __restrict__ xwb,
    const float* __restrict__ dwf, const float* __restrict__ dwb,
    ushortT* __restrict__ o1, ushortT* __restrict__ o2,
    ushortT* __restrict__ oxf, ushortT* __restrict__ oxb,
    ushortT* __restrict__ odf, ushortT* __restrict__ odb)
{
    int i = blockIdx.x * 256 + threadIdx.x;
    if (i < n1) { o1[i] = f2bf(w1[i]); return; }
    i -= n1;
    if (i < n2) { o2[i] = f2bf(w2[i]); return; }
    i -= n2;
    const int nx = NDBCP * DI_;
    if (i < 2 * nx) {
        int which = i >= nx;
        int j = which ? (i - nx) : i;
        int row = j / DI_;
        const float* src = which ? xwb : xwf;
        ushortT* dst = which ? oxb : oxf;
        dst[j] = (row < NDBC_) ? f2bf(src[j]) : (ushortT)0;
        return;
    }
    i -= 2 * nx;
    const int nd = DI_ * 32;
    if (i < 2 * nd) {
        int which = i >= nd;
        int j = which ? (i - nd) : i;
        int row = j >> 5, col = j & 31;
        const float* src = which ? dwb : dwf;
        ushortT* dst = which ? odb : odf;
        dst[j] = (col < RDT_) ? f2bf(src[row * RDT_ + col]) : (ushortT)0;
    }
}

// ---------------------------------------------------------------------------
// LayerNorm: one wave per row of 384; block = 4 rows. Writes bf16.
// ---------------------------------------------------------------------------
__global__ __launch_bounds__(256) void ln_kernel(
    const float* __restrict__ x, const float* __restrict__ w,
    const float* __restrict__ b, ushortT* __restrict__ xn,
    int row0, int nrows)
{
    int r = blockIdx.x * 4 + (threadIdx.x >> 6);
    if (r >= nrows) return;
    int lane = threadIdx.x & 63;
    const float* xr = x + (size_t)(row0 + r) * DM_;
    float v[6];
    float s = 0.0f;
#pragma unroll
    for (int i = 0; i < 6; i++) { v[i] = xr[lane + 64 * i]; s += v[i]; }
#pragma unroll
    for (int o = 32; o > 0; o >>= 1) s += __shfl_down(s, o, 64);
    s = __shfl(s, 0, 64);
    float mu = s * (1.0f / DM_);
    float q = 0.0f;
#pragma unroll
    for (int i = 0; i < 6; i++) { float d = v[i] - mu; q += d * d; }
#pragma unroll
    for (int o = 32; o > 0; o >>= 1) q += __shfl_down(q, o, 64);
    q = __shfl(q, 0, 64);
    float rstd = rsqrtf(q * (1.0f / DM_) + 1e-5f);
    ushortT* outp = xn + (size_t)r * DM_;
#pragma unroll
    for (int i = 0; i < 6; i++) {
        int c = lane + 64 * i;
        outp[c] = f2bf((v[i] - mu) * rstd * w[c] + b[c]);
    }
}

// ---------------------------------------------------------------------------
// bf16 MFMA GEMM (m97-style, XOR-swizzled LDS): C = [Aa | Ab] * W^T (+ R)
// OB: write bf16 output (XZ) instead of fp32.
// ---------------------------------------------------------------------------
template <int BM, int BN, int WR, int WC, bool CAT, bool RES, bool OB>
__global__ __launch_bounds__(256) void gemm_mfma(
    const ushortT* __restrict__ Aa, const ushortT* __restrict__ Ab_,
    const ushortT* __restrict__ W, const float* __restrict__ R,
    void* __restrict__ Cv, int M, int N, int Khalf)
{
    constexpr int WTM = BM / WR;
    constexpr int WTN = BN / WC;
    constexpr int FM = WTM / 16;
    constexpr int FN = WTN / 16;
    __shared__ ushortT As[BM * 32];
    __shared__ ushortT Ws[BN * 32];
    int tid = threadIdx.x;
    int bm = blockIdx.x * BM, bn = blockIdx.y * BN;
    int wave = tid >> 6, lane = tid & 63;
    int wm = wave % WR, wn = wave / WR;
    f32x4 acc[FM][FN] = {};
    int Ktot = CAT ? 2 * Khalf : Khalf;
    int lrow = lane >> 2;
    int lk = stage_sw(lane);

    for (int k0 = 0; k0 < Ktot; k0 += 32) {
        const ushortT* Asrc = (!CAT || k0 < Khalf) ? Aa : Ab_;
        int ka = (!CAT || k0 < Khalf) ? k0 : (k0 - Khalf);
        __syncthreads();
#pragma unroll
        for (int c = 0; c < BM / 64; c++) {
            int ch = c * 4 + wave;
            int row = ch * 16 + lrow;
            stage16(Asrc + (size_t)(bm + row) * Khalf + ka + lk, &As[ch * 16 * 32]);
        }
#pragma unroll
        for (int c = 0; c < BN / 64; c++) {
            int ch = c * 4 + wave;
            int row = ch * 16 + lrow;
            stage16(W + (size_t)(bn + row) * Khalf + ka + lk, &Ws[ch * 16 * 32]);
        }
        __syncthreads();
        int rsw = read_sw(lane);
        int mb = (wm * WTM + (lane & 15)) * 32 + rsw;
        int nb = (wn * WTN + (lane & 15)) * 32 + rsw;
        bf16x8 af[FM], bfr[FN];
#pragma unroll
        for (int mi = 0; mi < FM; mi++) af[mi] = *(bf16x8*)&As[mb + mi * 16 * 32];
#pragma unroll
        for (int ni = 0; ni < FN; ni++) bfr[ni] = *(bf16x8*)&Ws[nb + ni * 16 * 32];
#pragma unroll
        for (int mi = 0; mi < FM; mi++)
#pragma unroll
            for (int ni = 0; ni < FN; ni++)
                acc[mi][ni] = __builtin_amdgcn_mfma_f32_16x16x32_bf16(
                    af[mi], bfr[ni], acc[mi][ni], 0, 0, 0);
    }

#pragma unroll
    for (int mi = 0; mi < FM; mi++) {
        int row = bm + wm * WTM + 16 * mi + (lane >> 4) * 4;
#pragma unroll
        for (int ni = 0; ni < FN; ni++) {
            int col = bn + wn * WTN + 16 * ni + (lane & 15);
#pragma unroll
            for (int r = 0; r < 4; r++) {
                size_t o = (size_t)(row + r) * N + col;
                float v = acc[mi][ni][r];
                if (RES) v += R[o];
                if (OB) ((ushortT*)Cv)[o] = f2bf(v);
                else    ((float*)Cv)[o] = v;
            }
        }
    }
}

// ---------------------------------------------------------------------------
// Causal depthwise conv (K=4) + silu: bf16 XZ -> bf16 XH, 8 ch/thread.
// XH layout: [dir][gB*LN][DI] in j-space.
// ---------------------------------------------------------------------------
__global__ __launch_bounds__(256) void conv_kernel(
    const ushortT* __restrict__ XZ,
    const float* __restrict__ wf, const float* __restrict__ bf,
    const float* __restrict__ wb, const float* __restrict__ bb,
    ushortT* __restrict__ XH, int gB)
{
    const int D8 = DI_ / 8;  // 96
    int idx = blockIdx.x * 256 + threadIdx.x;
    int perdir = gB * LN_ * D8;
    int dir = 0;
    if (idx >= perdir) { idx -= perdir; dir = 1; }
    int d8 = idx % D8;
    int l = (idx / D8) & (LN_ - 1);
    int b = idx / (D8 * LN_);
    int d = d8 * 8;
    const float* cw = (dir ? wb : wf) + d * 4;
    const float* cb = (dir ? bb : bf) + d;

    float xv[4][8];
#pragma unroll
    for (int k = 0; k < 4; k++) {
        int j = l - 3 + k;
        if (j < 0) {
#pragma unroll
            for (int c = 0; c < 8; c++) xv[k][c] = 0.0f;
        } else {
            int ls = dir ? (LN_ - 1 - j) : j;
            ushort4 v = *(const ushort4*)(XZ + (size_t)(b * LN_ + ls) * (2 * DI_) + d);
            ushort4 v2 = *(const ushort4*)(XZ + (size_t)(b * LN_ + ls) * (2 * DI_) + d + 4);
            xv[k][0] = bf2f(v.x);  xv[k][1] = bf2f(v.y);
            xv[k][2] = bf2f(v.z);  xv[k][3] = bf2f(v.w);
            xv[k][4] = bf2f(v2.x); xv[k][5] = bf2f(v2.y);
            xv[k][6] = bf2f(v2.z); xv[k][7] = bf2f(v2.w);
        }
    }
    ushortT out[8];
#pragma unroll
    for (int c = 0; c < 8; c++) {
        float4 w4 = *(const float4*)(cw + c * 4);
        float s = cb[c];
        s = fmaf(xv[0][c], w4.x, s);
        s = fmaf(xv[1][c], w4.y, s);
        s = fmaf(xv[2][c], w4.z, s);
        s = fmaf(xv[3][c], w4.w, s);
        out[c] = f2bf(silu_f(s));
    }
    ushortT* op = XH + ((size_t)dir * gB * LN_ + (size_t)(b * LN_ + l)) * DI_ + d;
    *(ushort4*)(op + 0) = make_ushort4(out[0], out[1], out[2], out[3]);
    *(ushort4*)(op + 4) = make_ushort4(out[4], out[5], out[6], out[7]);
}

// ---------------------------------------------------------------------------
// xproj MFMA (XOR-swizzled LDS): C[dir][M x 64] = XH * Wpad^T; also writes
// DT24 (bf16 dt-cols, zero-padded to 32) for the dt GEMM.
// ---------------------------------------------------------------------------
__global__ __launch_bounds__(256) void xproj_mfma(
    const ushortT* __restrict__ XH, const ushortT* __restrict__ Wf,
    const ushortT* __restrict__ Wb, float* __restrict__ Cf,
    float* __restrict__ Cb, ushortT* __restrict__ DT24, int mblocksPerDir)
{
    __shared__ ushortT As[64 * 32];
    __shared__ ushortT Ws[64 * 32];
    int blk = blockIdx.x;
    int dir = blk >= mblocksPerDir;
    const ushortT* W = dir ? Wb : Wf;
    float* C = dir ? Cb : Cf;
    int bmG = blk * 64;
    int bmC = (blk - dir * mblocksPerDir) * 64;
    int tid = threadIdx.x, wave = tid >> 6, lane = tid & 63;
    f32x4 acc[4] = {};
    int lrow = lane >> 2;
    int lk = stage_sw(lane);
    int rsw = read_sw(lane);

    for (int k0 = 0; k0 < DI_; k0 += 32) {
        __syncthreads();
        stage16(XH + (size_t)(bmG + wave * 16 + lrow) * DI_ + k0 + lk, &As[wave * 16 * 32]);
        stage16(W + (size_t)(wave * 16 + lrow) * DI_ + k0 + lk, &Ws[wave * 16 * 32]);
        __syncthreads();
        bf16x8 bfr = *(bf16x8*)&Ws[(wave * 16 + (lane & 15)) * 32 + rsw];
#pragma unroll
        for (int mi = 0; mi < 4; mi++) {
            bf16x8 af = *(bf16x8*)&As[(mi * 16 + (lane & 15)) * 32 + rsw];
            acc[mi] = __builtin_amdgcn_mfma_f32_16x16x32_bf16(af, bfr, acc[mi], 0, 0, 0);
        }
    }
#pragma unroll
    for (int mi = 0; mi < 4; mi++) {
        int row = bmC + 16 * mi + (lane >> 4) * 4;
        int col = wave * 16 + (lane & 15);
#pragma unroll
        for (int r = 0; r < 4; r++)
            C[(size_t)(row + r) * NDBCP + col] = acc[mi][r];
    }
    if (wave < 2) {
        ushortT* dtp = DT24 + (size_t)dir * (size_t)(mblocksPerDir * 64) * 32;
        int col = wave * 16 + (lane & 15);
#pragma unroll
        for (int mi = 0; mi < 4; mi++) {
            int row = bmC + 16 * mi + (lane >> 4) * 4;
#pragma unroll
            for (int r = 0; r < 4; r++)
                dtp[(size_t)(row + r) * 32 + col] =
                    (col < RDT_) ? f2bf(acc[mi][r]) : (ushortT)0;
        }
    }
}

// ---------------------------------------------------------------------------
// dt GEMM + UD pack (XOR-swizzled LDS): dtraw = DT24 @ dtw_pad^T (K=32);
// UD = pack(bf16(softplus(dtraw+dtb)), XH).  BM=128, BN=64.
// ---------------------------------------------------------------------------
__global__ __launch_bounds__(256) void dtud_kernel(
    const ushortT* __restrict__ DT24, const ushortT* __restrict__ WDtf,
    const ushortT* __restrict__ WDtb,
    const float* __restrict__ dtbf, const float* __restrict__ dtbb,
    const ushortT* __restrict__ XH, uint32_t* __restrict__ UD, int rows)
{
    __shared__ ushortT As[128 * 32];
    __shared__ ushortT Ws[64 * 32];
    int dir = blockIdx.z;
    int bm = blockIdx.x * 128;
    int bn = blockIdx.y * 64;
    const ushortT* A = DT24 + (size_t)dir * rows * 32;
    const ushortT* W = dir ? WDtb : WDtf;
    const float* dtb = dir ? dtbb : dtbf;
    const ushortT* xh = XH + (size_t)dir * rows * DI_;
    uint32_t* ud = UD + (size_t)dir * rows * DI_;
    int tid = threadIdx.x, wave = tid >> 6, lane = tid & 63;
    int lrow = lane >> 2, lk = stage_sw(lane);
    int rsw = read_sw(lane);

    stage16(A + (size_t)(bm + wave * 16 + lrow) * 32 + lk, &As[wave * 16 * 32]);
    stage16(A + (size_t)(bm + 64 + wave * 16 + lrow) * 32 + lk, &As[(64 + wave * 16) * 32]);
    stage16(W + (size_t)(bn + wave * 16 + lrow) * 32 + lk, &Ws[wave * 16 * 32]);
    __syncthreads();

    f32x4 acc[2][4] = {};
    bf16x8 bfr[4];
#pragma unroll
    for (int ni = 0; ni < 4; ni++)
        bfr[ni] = *(bf16x8*)&Ws[(ni * 16 + (lane & 15)) * 32 + rsw];
#pragma unroll
    for (int mi = 0; mi < 2; mi++) {
        bf16x8 af = *(bf16x8*)&As[(wave * 32 + mi * 16 + (lane & 15)) * 32 + rsw];
#pragma unroll
        for (int ni = 0; ni < 4; ni++)
            acc[mi][ni] = __builtin_amdgcn_mfma_f32_16x16x32_bf16(
                af, bfr[ni], acc[mi][ni], 0, 0, 0);
    }
#pragma unroll
    for (int ni = 0; ni < 4; ni++) {
        int d = bn + ni * 16 + (lane & 15);
        float bias = dtb[d];
#pragma unroll
        for (int mi = 0; mi < 2; mi++) {
            int rb = bm + wave * 32 + mi * 16 + (lane >> 4) * 4;
#pragma unroll
            for (int r = 0; r < 4; r++) {
                int row = rb + r;
                float dt = softplus_f(acc[mi][ni][r] + bias);
                float u = bf2f(xh[(size_t)row * DI_ + d]);
                ud[(size_t)row * DI_ + d] =
                    ((uint32_t)f2bf(dt) << 16) | (uint32_t)f2bf(u);
            }
        }
    }
}

// ---------------------------------------------------------------------------
// Chunked selective scan, phase 1: 8-wide distance-1 prefetch;
// stages only B cols; publishes packed bf16 (dec<<16 | hs1).
// A=-(n+1)*a1 fast path.
// ---------------------------------------------------------------------------
__global__ __launch_bounds__(256) void scan1_kernel(
    const uint32_t* __restrict__ UD,
    const float* __restrict__ dbcf, const float* __restrict__ dbcb,
    const float* __restrict__ alogf, const float* __restrict__ alogb,
    uint32_t* __restrict__ SD, int gB)
{
    int bid = blockIdx.x;
    int c = bid % NC_; bid /= NC_;
    int dchunk = bid % 3; bid /= 3;
    int b = bid % gB;
    int dir = bid / gB;
    int d = dchunk * 256 + threadIdx.x;

    const float* dbc  = dir ? dbcb : dbcf;
    const float* alog = dir ? alogb : alogf;

    float An[NS_];
#pragma unroll
    for (int n = 0; n < NS_; n++) An[n] = -__expf(alog[d * NS_ + n]);
    float a1 = An[0];
    bool pk = true;
#pragma unroll
    for (int n = 0; n < NS_; n++)
        pk = pk && (fabsf(An[n] - (float)(n + 1) * a1) <=
                    1e-3f * (float)(n + 1) * fabsf(a1) + 1e-6f);
    pk = (bool)__all((int)pk);

    __shared__ float sB[LC_ * 16];
    int rb = b * LN_ + c * LC_;
    int jb = c * LC_;
    {
        int row = threadIdx.x >> 2, c4 = (threadIdx.x & 3) * 4;
        *(float4*)&sB[row * 16 + c4] =
            *(const float4*)(dbc + (size_t)(rb + row) * NDBCP + RDT_ + c4);
    }
    __syncthreads();

    float h[NS_];
#pragma unroll
    for (int n = 0; n < NS_; n++) h[n] = 0.0f;
    float S = 0.0f;
    const uint32_t* udp = UD + (size_t)((dir * gB + b) * LN_ + jb) * DI_ + d;

    if (pk) {
        uint32_t ud8[8];
#pragma unroll
        for (int i = 0; i < 8; i++) ud8[i] = udp[i * DI_];
        for (int lt = 0; lt < LC_; lt += 8) {
            uint32_t cur[8];
#pragma unroll
            for (int i = 0; i < 8; i++) cur[i] = ud8[i];
            if (lt + 8 < LC_) {
#pragma unroll
                for (int i = 0; i < 8; i++) ud8[i] = udp[(lt + 8 + i) * DI_];
            }
#pragma unroll
            for (int i = 0; i < 8; i++) {
                int lr = lt + i;
                const float4* Bp4 = (const float4*)&sB[lr * 16];
                float4 B0 = Bp4[0], B1 = Bp4[1], B2 = Bp4[2], B3 = Bp4[3];
                float Bv[NS_] = {B0.x, B0.y, B0.z, B0.w, B1.x, B1.y, B1.z, B1.w,
                                 B2.x, B2.y, B2.z, B2.w, B3.x, B3.y, B3.z, B3.w};
                float u = bf2f((ushortT)(cur[i] & 0xffffu));
                float dt = bf2f((ushortT)(cur[i] >> 16));
                S += dt;
                float du = dt * u;
                float q1 = __expf(dt * a1);
                float q2 = q1 * q1, q4 = q2 * q2, q8 = q4 * q4;
                float p2 = q2, p3 = q2 * q1, p5 = q4 * q1, p6 = q4 * q2, p7 = q4 * p3;
                float pw[NS_] = {q1, p2, p3, q4, p5, p6, p7, q8,
                                 q8 * q1, q8 * p2, q8 * p3, q8 * q4,
                                 q8 * p5, q8 * p6, q8 * p7, q8 * q8};
#pragma unroll
                for (int n = 0; n < NS_; n++)
                    h[n] = fmaf(h[n], pw[n], du * Bv[n]);
            }
        }
        float q1 = __expf(S * a1);
        float q2 = q1 * q1, q4 = q2 * q2, q8 = q4 * q4;
        float p2 = q2, p3 = q2 * q1, p5 = q4 * q1, p6 = q4 * q2, p7 = q4 * p3;
        float pw[NS_] = {q1, p2, p3, q4, p5, p6, p7, q8,
                         q8 * q1, q8 * p2, q8 * p3, q8 * q4,
                         q8 * p5, q8 * p6, q8 * p7, q8 * q8};
        int si = (((dir * gB + b) * NC_ + c) * DI_ + d) * NS_;
#pragma unroll
        for (int n = 0; n < NS_; n++)
            SD[si + n] = ((uint32_t)f2bf(pw[n]) << 16) | (uint32_t)f2bf(h[n]);
    } else {
        for (int lr = 0; lr < LC_; lr++) {
            const float* rowp = &sB[lr * 16];
            uint32_t udv = udp[lr * DI_];
            float u = bf2f((ushortT)(udv & 0xffffu));
            float dt = bf2f((ushortT)(udv >> 16));
            S += dt;
            float du = dt * u;
#pragma unroll
            for (int n = 0; n < NS_; n++)
                h[n] = fmaf(h[n], __expf(dt * An[n]), du * rowp[n]);
        }
        int si = (((dir * gB + b) * NC_ + c) * DI_ + d) * NS_;
#pragma unroll
        for (int n = 0; n < NS_; n++)
            SD[si + n] = ((uint32_t)f2bf(__expf(An[n] * S)) << 16) |
                         (uint32_t)f2bf(h[n]);
    }
}

__global__ __launch_bounds__(256) void scan2_kernel(
    const uint32_t* __restrict__ SD, ushortT* __restrict__ hin, int gB)
{
    int e = blockIdx.x * 256 + threadIdx.x;
    int n = e & 15; int e2 = e >> 4;
    int d = e2 % DI_; e2 /= DI_;
    int b = e2 % gB; int dir = e2 / gB;
    int base = (((dir * gB + b) * NC_) * DI_ + d) * NS_ + n;
    float h = 0.0f;
    const int cs = DI_ * NS_;
    for (int c = 0; c < NC_; c++) {
        int idx = base + c * cs;
        uint32_t sd = SD[idx];
        hin[idx] = f2bf(h);
        h = fmaf(h, bf2f((ushortT)(sd >> 16)), bf2f((ushortT)(sd & 0xffffu)));
    }
}

// Phase 3: distance-2 pipelined 8-wide prefetch (UD + z), fully unrolled so
// the double-buffer index is compile-time; h seeded from bf16 hin.
__global__ __launch_bounds__(256) void scan3_kernel(
    const uint32_t* __restrict__ UD, const ushortT* __restrict__ XZ,
    const float* __restrict__ dbcf, const float* __restrict__ dbcb,
    const float* __restrict__ alogf, const float* __restrict__ dvf,
    const float* __restrict__ alogb, const float* __restrict__ dvb,
    const ushortT* __restrict__ hin,
    ushortT* __restrict__ yf, ushortT* __restrict__ yb, int gB)
{
    int bid = blockIdx.x;
    int c = bid % NC_; bid /= NC_;
    int dchunk = bid % 3; bid /= 3;
    int b = bid % gB;
    int dir = bid / gB;
    int d = dchunk * 256 + threadIdx.x;

    const float* dbc  = dir ? dbcb : dbcf;
    const float* alog = dir ? alogb : alogf;
    float Dd          = (dir ? dvb : dvf)[d];
    ushortT* y        = dir ? yb : yf;

    float An[NS_];
#pragma unroll
    for (int n = 0; n < NS_; n++) An[n] = -__expf(alog[d * NS_ + n]);
    float a1 = An[0];
    bool pk = true;
#pragma unroll
    for (int n = 0; n < NS_; n++)
        pk = pk && (fabsf(An[n] - (float)(n + 1) * a1) <=
                    1e-3f * (float)(n + 1) * fabsf(a1) + 1e-6f);
    pk = (bool)__all((int)pk);

    __shared__ float sBC[LC_ * 32];
    int rb = b * LN_ + c * LC_;
    int jb = c * LC_;
#pragma unroll
    for (int i = 0; i < 2; i++) {
        int idx = threadIdx.x + 256 * i;
        int row = idx >> 3, c4 = (idx & 7) * 4;
        *(float4*)&sBC[row * 32 + c4] =
            *(const float4*)(dbc + (size_t)(rb + row) * NDBCP + RDT_ + c4);
    }
    __syncthreads();

    int si = (((dir * gB + b) * NC_ + c) * DI_ + d) * NS_;
    float h[NS_];
#pragma unroll
    for (int n = 0; n < NS_; n++) h[n] = bf2f(hin[si + n]);
    const uint32_t* udp = UD + (size_t)((dir * gB + b) * LN_ + jb) * DI_ + d;

    if (pk) {
        uint32_t udb[2][8];
        ushortT zbf[2][8];
#pragma unroll
        for (int i = 0; i < 8; i++) {
            udb[0][i] = udp[i * DI_];
            int j = jb + i;
            int lo = dir ? (LN_ - 1 - j) : j;
            zbf[0][i] = XZ[(size_t)(b * LN_ + lo) * (2 * DI_) + DI_ + d];
        }
#pragma unroll
        for (int i = 0; i < 8; i++) {
            udb[1][i] = udp[(8 + i) * DI_];
            int j = jb + 8 + i;
            int lo = dir ? (LN_ - 1 - j) : j;
            zbf[1][i] = XZ[(size_t)(b * LN_ + lo) * (2 * DI_) + DI_ + d];
        }
#pragma unroll
        for (int gq = 0; gq < LC_ / 8; gq++) {
            const int p = gq & 1;           // compile-time after full unroll
            uint32_t cud[8];
            ushortT cz[8];
#pragma unroll
            for (int i = 0; i < 8; i++) { cud[i] = udb[p][i]; cz[i] = zbf[p][i]; }
            if (gq + 2 < LC_ / 8) {
#pragma unroll
                for (int i = 0; i < 8; i++) {
                    int jj = (gq + 2) * 8 + i;
                    udb[p][i] = udp[jj * DI_];
                    int j = jb + jj;
                    int lo = dir ? (LN_ - 1 - j) : j;
                    zbf[p][i] = XZ[(size_t)(b * LN_ + lo) * (2 * DI_) + DI_ + d];
                }
            }
            int lt = gq * 8;
#pragma unroll
            for (int i = 0; i < 8; i++) {
                int lr = lt + i;
                const float4* rp4 = (const float4*)&sBC[lr * 32];
                float4 B0 = rp4[0], B1 = rp4[1], B2 = rp4[2], B3 = rp4[3];
                float4 C0 = rp4[4], C1 = rp4[5], C2 = rp4[6], C3 = rp4[7];
                float Bv[NS_] = {B0.x, B0.y, B0.z, B0.w, B1.x, B1.y, B1.z, B1.w,
                                 B2.x, B2.y, B2.z, B2.w, B3.x, B3.y, B3.z, B3.w};
                float Cw[NS_] = {C0.x, C0.y, C0.z, C0.w, C1.x, C1.y, C1.z, C1.w,
                                 C2.x, C2.y, C2.z, C2.w, C3.x, C3.y, C3.z, C3.w};
                float u = bf2f((ushortT)(cud[i] & 0xffffu));
                float dt = bf2f((ushortT)(cud[i] >> 16));
                float du = dt * u;
                float q1 = __expf(dt * a1);
                float q2 = q1 * q1, q4 = q2 * q2, q8 = q4 * q4;
                float p2 = q2, p3 = q2 * q1, p5 = q4 * q1, p6 = q4 * q2, p7 = q4 * p3;
                float pw[NS_] = {q1, p2, p3, q4, p5, p6, p7, q8,
                                 q8 * q1, q8 * p2, q8 * p3, q8 * q4,
                                 q8 * p5, q8 * p6, q8 * p7, q8 * q8};
                float y0 = 0.f, y1 = 0.f, y2 = 0.f, y3 = 0.f;
#pragma unroll
                for (int n = 0; n < NS_; n += 4) {
                    h[n + 0] = fmaf(h[n + 0], pw[n + 0], du * Bv[n + 0]);
                    h[n + 1] = fmaf(h[n + 1], pw[n + 1], du * Bv[n + 1]);
                    h[n + 2] = fmaf(h[n + 2], pw[n + 2], du * Bv[n + 2]);
                    h[n + 3] = fmaf(h[n + 3], pw[n + 3], du * Bv[n + 3]);
                    y0 = fmaf(h[n + 0], Cw[n + 0], y0);
                    y1 = fmaf(h[n + 1], Cw[n + 1], y1);
                    y2 = fmaf(h[n + 2], Cw[n + 2], y2);
                    y3 = fmaf(h[n + 3], Cw[n + 3], y3);
                }
                float yv = ((y0 + y1) + (y2 + y3)) + u * Dd;
                int j = jb + lr;
                int lo = dir ? (LN_ - 1 - j) : j;
                float z = bf2f(cz[i]);
                y[(b * LN_ + lo) * DI_ + d] = f2bf(yv * silu_f(z));
            }
        }
    } else {
        for (int lr = 0; lr < LC_; lr++) {
            const float* rowp = &sBC[lr * 32];
            uint32_t ud = udp[lr * DI_];
            float u = bf2f((ushortT)(ud & 0xffffu));
            float dt = bf2f((ushortT)(ud >> 16));
            float du = dt * u;
            float y0 = 0.f, y1 = 0.f, y2 = 0.f, y3 = 0.f;
#pragma unroll
            for (int n = 0; n < NS_; n += 4) {
                h[n + 0] = fmaf(h[n + 0], __expf(dt * An[n + 0]), du * rowp[n + 0]);
                h[n + 1] = fmaf(h[n + 1], __expf(dt * An[n + 1]), du * rowp[n + 1]);
                h[n + 2] = fmaf(h[n + 2], __expf(dt * An[n + 2]), du * rowp[n + 2]);
                h[n + 3] = fmaf(h[n + 3], __expf(dt * An[n + 3]), du * rowp[n + 3]);
                y0 = fmaf(h[n + 0], rowp[16 + n + 0], y0);
                y1 = fmaf(h[n + 1], rowp[16 + n + 1], y1);
                y2 = fmaf(h[n + 2], rowp[16 + n + 2], y2);
                y3 = fmaf(h[n + 3], rowp[16 + n + 3], y3);
            }
            float yv = ((y0 + y1) + (y2 + y3)) + u * Dd;
            int j = jb + lr;
            int lo = dir ? (LN_ - 1 - j) : j;
            float z = bf2f(XZ[(size_t)(b * LN_ + lo) * (2 * DI_) + DI_ + d]);
            y[(b * LN_ + lo) * DI_ + d] = f2bf(yv * silu_f(z));
        }
    }
}

// ---------------------------------------------------------------------------
// Host launcher.
// ---------------------------------------------------------------------------
extern "C" void kernel_launch(void* const* d_in, const int* in_sizes, int n_in,
                              void* d_out, int out_size, void* d_ws, size_t ws_size,
                              hipStream_t stream)
{
    const float* x         = (const float*)d_in[0];
    const float* ln_w      = (const float*)d_in[1];
    const float* ln_b      = (const float*)d_in[2];
    const float* in_proj_w = (const float*)d_in[3];
    const float* out_proj_w= (const float*)d_in[4];
    const float* conv_wf   = (const float*)d_in[5];
    const float* conv_bf   = (const float*)d_in[6];
    const float* xproj_f   = (const float*)d_in[7];
    const float* dt_wf     = (const float*)d_in[8];
    const float* dt_bf     = (const float*)d_in[9];
    const float* alog_f    = (const float*)d_in[10];
    const float* dv_f      = (const float*)d_in[11];
    const float* conv_wb   = (const float*)d_in[12];
    const float* conv_bb   = (const float*)d_in[13];
    const float* xproj_b   = (const float*)d_in[14];
    const float* dt_wb     = (const float*)d_in[15];
    const float* dt_bb     = (const float*)d_in[16];
    const float* alog_b    = (const float*)d_in[17];
    const float* dv_b      = (const float*)d_in[18];
    float* outp = (float*)d_out;

    const int n_w1 = 2 * DI_ * DM_;
    const int n_w2 = DM_ * DI_;
    const int n_wx = NDBCP * DI_;
    const int n_wd = DI_ * 32;

    uint8_t* base = (uint8_t*)d_ws;
    size_t off = 0;
    auto alloc = [&](size_t nbytes) {
        uint8_t* r = base + off;
        off = (off + nbytes + 255) & ~(size_t)255;
        return r;
    };
    ushortT* WbIn  = (ushortT*)alloc((size_t)n_w1 * 2);
    ushortT* WbOut = (ushortT*)alloc((size_t)n_w2 * 2);
    ushortT* WbXf  = (ushortT*)alloc((size_t)n_wx * 2);
    ushortT* WbXb  = (ushortT*)alloc((size_t)n_wx * 2);
    ushortT* WbDtf = (ushortT*)alloc((size_t)n_wd * 2);
    ushortT* WbDtb = (ushortT*)alloc((size_t)n_wd * 2);
    size_t fixed_bytes = off;

    size_t per_b_bytes = 21ull * 1024 * 1024;
    int g = BN_;
    while (g > 1 && fixed_bytes + (size_t)g * per_b_bytes + (1ull << 20) > ws_size) g >>= 1;

    wconv_kernel<<<(n_w1 + n_w2 + 2 * n_wx + 2 * n_wd + 255) / 256, 256, 0, stream>>>(
        in_proj_w, n_w1, out_proj_w, n_w2, xproj_f, xproj_b, dt_wf, dt_wb,
        WbIn, WbOut, WbXf, WbXb, WbDtf, WbDtb);

    for (int b0 = 0; b0 < BN_; b0 += g) {
        int rows = g * LN_;
        off = fixed_bytes;
        ushortT* XNb  = (ushortT*)alloc((size_t)rows * DM_ * 2);
        ushortT* XZ   = (ushortT*)alloc((size_t)rows * 2 * DI_ * 2);
        ushortT* XH   = (ushortT*)alloc((size_t)2 * rows * DI_ * 2);
        float* DBCf   = (float*)alloc((size_t)rows * NDBCP * 4);
        float* DBCb   = (float*)alloc((size_t)rows * NDBCP * 4);
        ushortT* DT24 = (ushortT*)alloc((size_t)2 * rows * 32 * 2);
        uint32_t* UD  = (uint32_t*)alloc((size_t)2 * rows * DI_ * 4);
        size_t st_n   = (size_t)2 * g * NC_ * DI_ * NS_;
        uint32_t* SD  = (uint32_t*)alloc(st_n * 4);
        ushortT* HIN  = (ushortT*)alloc(st_n * 2);
        ushortT* Yf   = (ushortT*)alloc((size_t)rows * DI_ * 2);
        ushortT* Yb   = (ushortT*)alloc((size_t)rows * DI_ * 2);
        int row0 = b0 * LN_;

        ln_kernel<<<rows / 4, 256, 0, stream>>>(x, ln_w, ln_b, XNb, row0, rows);

        gemm_mfma<128, 128, 2, 2, false, false, true>
            <<<dim3(rows / 128, (2 * DI_) / 128), 256, 0, stream>>>(
            XNb, nullptr, WbIn, nullptr, XZ, rows, 2 * DI_, DM_);

        conv_kernel<<<(2 * rows * (DI_ / 8)) / 256, 256, 0, stream>>>(
            XZ, conv_wf, conv_bf, conv_wb, conv_bb, XH, g);

        xproj_mfma<<<2 * (rows / 64), 256, 0, stream>>>(
            XH, WbXf, WbXb, DBCf, DBCb, DT24, rows / 64);

        dtud_kernel<<<dim3(rows / 128, DI_ / 64, 2), 256, 0, stream>>>(
            DT24, WbDtf, WbDtb, dt_bf, dt_bb, XH, UD, rows);

        scan1_kernel<<<2 * g * 3 * NC_, 256, 0, stream>>>(
            UD, DBCf, DBCb, alog_f, alog_b, SD, g);

        scan2_kernel<<<(2 * g * DI_ * NS_) / 256, 256, 0, stream>>>(SD, HIN, g);

        scan3_kernel<<<2 * g * 3 * NC_, 256, 0, stream>>>(
            UD, XZ, DBCf, DBCb, alog_f, dv_f, alog_b, dv_b,
            HIN, Yf, Yb, g);

        gemm_mfma<64, 128, 1, 4, true, true, false>
            <<<dim3(rows / 64, DM_ / 128), 256, 0, stream>>>(
            Yf, Yb, WbOut, x + (size_t)row0 * DM_,
            outp + (size_t)row0 * DM_, rows, DM_, DI_);
    }
}

// Round 13
// 485.367 us; speedup vs baseline: 1.1845x; 1.1845x over previous
//
#include <hip/hip_runtime.h>
#include <cstdint>
#include <cstddef>

// Problem constants
#define BN_   16
#define LN_   1024
#define DM_   384
#define DI_   768
#define NS_   16
#define RDT_  24
#define NDBC_ 56
#define NDBCP 64     // padded dbc stride
#define NC_   16
#define LC_   64

typedef unsigned short ushortT;
typedef short bf16x8 __attribute__((ext_vector_type(8)));
typedef float f32x4 __attribute__((ext_vector_type(4)));

typedef __attribute__((address_space(3))) uint32_t lds_u32_t;
typedef __attribute__((address_space(1))) const uint32_t glb_u32_t;

static __device__ __forceinline__ void stage16(const void* g, void* lds) {
    __builtin_amdgcn_global_load_lds(
        (glb_u32_t*)(uintptr_t)g,
        (lds_u32_t*)(uint32_t)(uintptr_t)lds,
        16, 0, 0);
}

// XOR-swizzle helpers for 16B granules in 64B rows (kills 8-way ds_read_b128
// bank conflicts -> free 2-way). Stage: lane l sources global granule
// (l&3)^((l>>3)&3). Read: fragment granule q at row m lives at q^((m>>1)&3).
static __device__ __forceinline__ int stage_sw(int lane) {
    return ((lane & 3) ^ ((lane >> 3) & 3)) * 8;   // ushort offset
}
static __device__ __forceinline__ int read_sw(int lane) {
    return (((lane >> 4) ^ (((lane & 15) >> 1) & 3)) * 8);  // ushort offset
}

static __device__ __forceinline__ float silu_f(float x) {
    return x / (1.0f + __expf(-x));
}
// fast softplus: ln(1+e^s) = max(s,0) + ln(1+e^-|s|)
static __device__ __forceinline__ float softplus_f(float s) {
    return fmaxf(s, 0.0f) + __logf(1.0f + __expf(-fabsf(s)));
}
static __device__ __forceinline__ ushortT f2bf(float f) {
    union { float f; uint32_t u; } v; v.f = f;
    uint32_t u = v.u;
    uint32_t r = u + 0x7fffu + ((u >> 16) & 1u);
    return (ushortT)(r >> 16);
}
static __device__ __forceinline__ float bf2f(ushortT b) {
    union { uint32_t u; float f; } v; v.u = ((uint32_t)b) << 16;
    return v.f;
}

// ---------------------------------------------------------------------------
// Weight conversions: in_proj/out_proj fp32->bf16; xproj bf16 padded to 64
// rows; dt_w bf16 padded to 32 cols (24..31 zero).
// ---------------------------------------------------------------------------
__global__ __launch_bounds__(256) void wconv_kernel(
    const float* __restrict__ w1, int n1, const float* __restrict__ w2, int n2,
    const float* __restrict__ xwf, const float* __restrict__ xwb,
    const float* __restrict__ dwf, const float* __restrict__ dwb,
    ushortT* __restrict__ o1, ushortT* __restrict__ o2,
    ushortT* __restrict__ oxf, ushortT* __restrict__ oxb,
    ushortT* __restrict__ odf, ushortT* __restrict__ odb)
{
    int i = blockIdx.x * 256 + threadIdx.x;
    if (i < n1) { o1[i] = f2bf(w1[i]); return; }
    i -= n1;
    if (i < n2) { o2[i] = f2bf(w2[i]); return; }
    i -= n2;
    const int nx = NDBCP * DI_;
    if (i < 2 * nx) {
        int which = i >= nx;
        int j = which ? (i - nx) : i;
        int row = j / DI_;
        const float* src = which ? xwb : xwf;
        ushortT* dst = which ? oxb : oxf;
        dst[j] = (row < NDBC_) ? f2bf(src[j]) : (ushortT)0;
        return;
    }
    i -= 2 * nx;
    const int nd = DI_ * 32;
    if (i < 2 * nd) {
        int which = i >= nd;
        int j = which ? (i - nd) : i;
        int row = j >> 5, col = j & 31;
        const float* src = which ? dwb : dwf;
        ushortT* dst = which ? odb : odf;
        dst[j] = (col < RDT_) ? f2bf(src[row * RDT_ + col]) : (ushortT)0;
    }
}

// ---------------------------------------------------------------------------
// LayerNorm: one wave per row of 384; block = 4 rows. Writes bf16.
// ---------------------------------------------------------------------------
__global__ __launch_bounds__(256) void ln_kernel(
    const float* __restrict__ x, const float* __restrict__ w,
    const float* __restrict__ b, ushortT* __restrict__ xn,
    int row0, int nrows)
{
    int r = blockIdx.x * 4 + (threadIdx.x >> 6);
    if (r >= nrows) return;
    int lane = threadIdx.x & 63;
    const float* xr = x + (size_t)(row0 + r) * DM_;
    float v[6];
    float s = 0.0f;
#pragma unroll
    for (int i = 0; i < 6; i++) { v[i] = xr[lane + 64 * i]; s += v[i]; }
#pragma unroll
    for (int o = 32; o > 0; o >>= 1) s += __shfl_down(s, o, 64);
    s = __shfl(s, 0, 64);
    float mu = s * (1.0f / DM_);
    float q = 0.0f;
#pragma unroll
    for (int i = 0; i < 6; i++) { float d = v[i] - mu; q += d * d; }
#pragma unroll
    for (int o = 32; o > 0; o >>= 1) q += __shfl_down(q, o, 64);
    q = __shfl(q, 0, 64);
    float rstd = rsqrtf(q * (1.0f / DM_) + 1e-5f);
    ushortT* outp = xn + (size_t)r * DM_;
#pragma unroll
    for (int i = 0; i < 6; i++) {
        int c = lane + 64 * i;
        outp[c] = f2bf((v[i] - mu) * rstd * w[c] + b[c]);
    }
}

// ---------------------------------------------------------------------------
// bf16 MFMA GEMM (m97-style, XOR-swizzled LDS): C = [Aa | Ab] * W^T (+ R)
// OB: write bf16 output (XZ) instead of fp32.
// ---------------------------------------------------------------------------
template <int BM, int BN, int WR, int WC, bool CAT, bool RES, bool OB>
__global__ __launch_bounds__(256) void gemm_mfma(
    const ushortT* __restrict__ Aa, const ushortT* __restrict__ Ab_,
    const ushortT* __restrict__ W, const float* __restrict__ R,
    void* __restrict__ Cv, int M, int N, int Khalf)
{
    constexpr int WTM = BM / WR;
    constexpr int WTN = BN / WC;
    constexpr int FM = WTM / 16;
    constexpr int FN = WTN / 16;
    __shared__ ushortT As[BM * 32];
    __shared__ ushortT Ws[BN * 32];
    int tid = threadIdx.x;
    int bm = blockIdx.x * BM, bn = blockIdx.y * BN;
    int wave = tid >> 6, lane = tid & 63;
    int wm = wave % WR, wn = wave / WR;
    f32x4 acc[FM][FN] = {};
    int Ktot = CAT ? 2 * Khalf : Khalf;
    int lrow = lane >> 2;
    int lk = stage_sw(lane);

    for (int k0 = 0; k0 < Ktot; k0 += 32) {
        const ushortT* Asrc = (!CAT || k0 < Khalf) ? Aa : Ab_;
        int ka = (!CAT || k0 < Khalf) ? k0 : (k0 - Khalf);
        __syncthreads();
#pragma unroll
        for (int c = 0; c < BM / 64; c++) {
            int ch = c * 4 + wave;
            int row = ch * 16 + lrow;
            stage16(Asrc + (size_t)(bm + row) * Khalf + ka + lk, &As[ch * 16 * 32]);
        }
#pragma unroll
        for (int c = 0; c < BN / 64; c++) {
            int ch = c * 4 + wave;
            int row = ch * 16 + lrow;
            stage16(W + (size_t)(bn + row) * Khalf + ka + lk, &Ws[ch * 16 * 32]);
        }
        __syncthreads();
        int rsw = read_sw(lane);
        int mb = (wm * WTM + (lane & 15)) * 32 + rsw;
        int nb = (wn * WTN + (lane & 15)) * 32 + rsw;
        bf16x8 af[FM], bfr[FN];
#pragma unroll
        for (int mi = 0; mi < FM; mi++) af[mi] = *(bf16x8*)&As[mb + mi * 16 * 32];
#pragma unroll
        for (int ni = 0; ni < FN; ni++) bfr[ni] = *(bf16x8*)&Ws[nb + ni * 16 * 32];
#pragma unroll
        for (int mi = 0; mi < FM; mi++)
#pragma unroll
            for (int ni = 0; ni < FN; ni++)
                acc[mi][ni] = __builtin_amdgcn_mfma_f32_16x16x32_bf16(
                    af[mi], bfr[ni], acc[mi][ni], 0, 0, 0);
    }

#pragma unroll
    for (int mi = 0; mi < FM; mi++) {
        int row = bm + wm * WTM + 16 * mi + (lane >> 4) * 4;
#pragma unroll
        for (int ni = 0; ni < FN; ni++) {
            int col = bn + wn * WTN + 16 * ni + (lane & 15);
#pragma unroll
            for (int r = 0; r < 4; r++) {
                size_t o = (size_t)(row + r) * N + col;
                float v = acc[mi][ni][r];
                if (RES) v += R[o];
                if (OB) ((ushortT*)Cv)[o] = f2bf(v);
                else    ((float*)Cv)[o] = v;
            }
        }
    }
}

// ---------------------------------------------------------------------------
// Causal depthwise conv (K=4) + silu: bf16 XZ -> bf16 XH, 8 ch/thread.
// XH layout: [dir][gB*LN][DI] in j-space.
// ---------------------------------------------------------------------------
__global__ __launch_bounds__(256) void conv_kernel(
    const ushortT* __restrict__ XZ,
    const float* __restrict__ wf, const float* __restrict__ bf,
    const float* __restrict__ wb, const float* __restrict__ bb,
    ushortT* __restrict__ XH, int gB)
{
    const int D8 = DI_ / 8;  // 96
    int idx = blockIdx.x * 256 + threadIdx.x;
    int perdir = gB * LN_ * D8;
    int dir = 0;
    if (idx >= perdir) { idx -= perdir; dir = 1; }
    int d8 = idx % D8;
    int l = (idx / D8) & (LN_ - 1);
    int b = idx / (D8 * LN_);
    int d = d8 * 8;
    const float* cw = (dir ? wb : wf) + d * 4;
    const float* cb = (dir ? bb : bf) + d;

    float xv[4][8];
#pragma unroll
    for (int k = 0; k < 4; k++) {
        int j = l - 3 + k;
        if (j < 0) {
#pragma unroll
            for (int c = 0; c < 8; c++) xv[k][c] = 0.0f;
        } else {
            int ls = dir ? (LN_ - 1 - j) : j;
            ushort4 v = *(const ushort4*)(XZ + (size_t)(b * LN_ + ls) * (2 * DI_) + d);
            ushort4 v2 = *(const ushort4*)(XZ + (size_t)(b * LN_ + ls) * (2 * DI_) + d + 4);
            xv[k][0] = bf2f(v.x);  xv[k][1] = bf2f(v.y);
            xv[k][2] = bf2f(v.z);  xv[k][3] = bf2f(v.w);
            xv[k][4] = bf2f(v2.x); xv[k][5] = bf2f(v2.y);
            xv[k][6] = bf2f(v2.z); xv[k][7] = bf2f(v2.w);
        }
    }
    ushortT out[8];
#pragma unroll
    for (int c = 0; c < 8; c++) {
        float4 w4 = *(const float4*)(cw + c * 4);
        float s = cb[c];
        s = fmaf(xv[0][c], w4.x, s);
        s = fmaf(xv[1][c], w4.y, s);
        s = fmaf(xv[2][c], w4.z, s);
        s = fmaf(xv[3][c], w4.w, s);
        out[c] = f2bf(silu_f(s));
    }
    ushortT* op = XH + ((size_t)dir * gB * LN_ + (size_t)(b * LN_ + l)) * DI_ + d;
    *(ushort4*)(op + 0) = make_ushort4(out[0], out[1], out[2], out[3]);
    *(ushort4*)(op + 4) = make_ushort4(out[4], out[5], out[6], out[7]);
}

// ---------------------------------------------------------------------------
// xproj MFMA (XOR-swizzled LDS): C[dir][M x 64] = XH * Wpad^T; also writes
// DT24 (bf16 dt-cols, zero-padded to 32) for the dt GEMM.
// ---------------------------------------------------------------------------
__global__ __launch_bounds__(256) void xproj_mfma(
    const ushortT* __restrict__ XH, const ushortT* __restrict__ Wf,
    const ushortT* __restrict__ Wb, float* __restrict__ Cf,
    float* __restrict__ Cb, ushortT* __restrict__ DT24, int mblocksPerDir)
{
    __shared__ ushortT As[64 * 32];
    __shared__ ushortT Ws[64 * 32];
    int blk = blockIdx.x;
    int dir = blk >= mblocksPerDir;
    const ushortT* W = dir ? Wb : Wf;
    float* C = dir ? Cb : Cf;
    int bmG = blk * 64;
    int bmC = (blk - dir * mblocksPerDir) * 64;
    int tid = threadIdx.x, wave = tid >> 6, lane = tid & 63;
    f32x4 acc[4] = {};
    int lrow = lane >> 2;
    int lk = stage_sw(lane);
    int rsw = read_sw(lane);

    for (int k0 = 0; k0 < DI_; k0 += 32) {
        __syncthreads();
        stage16(XH + (size_t)(bmG + wave * 16 + lrow) * DI_ + k0 + lk, &As[wave * 16 * 32]);
        stage16(W + (size_t)(wave * 16 + lrow) * DI_ + k0 + lk, &Ws[wave * 16 * 32]);
        __syncthreads();
        bf16x8 bfr = *(bf16x8*)&Ws[(wave * 16 + (lane & 15)) * 32 + rsw];
#pragma unroll
        for (int mi = 0; mi < 4; mi++) {
            bf16x8 af = *(bf16x8*)&As[(mi * 16 + (lane & 15)) * 32 + rsw];
            acc[mi] = __builtin_amdgcn_mfma_f32_16x16x32_bf16(af, bfr, acc[mi], 0, 0, 0);
        }
    }
#pragma unroll
    for (int mi = 0; mi < 4; mi++) {
        int row = bmC + 16 * mi + (lane >> 4) * 4;
        int col = wave * 16 + (lane & 15);
#pragma unroll
        for (int r = 0; r < 4; r++)
            C[(size_t)(row + r) * NDBCP + col] = acc[mi][r];
    }
    if (wave < 2) {
        ushortT* dtp = DT24 + (size_t)dir * (size_t)(mblocksPerDir * 64) * 32;
        int col = wave * 16 + (lane & 15);
#pragma unroll
        for (int mi = 0; mi < 4; mi++) {
            int row = bmC + 16 * mi + (lane >> 4) * 4;
#pragma unroll
            for (int r = 0; r < 4; r++)
                dtp[(size_t)(row + r) * 32 + col] =
                    (col < RDT_) ? f2bf(acc[mi][r]) : (ushortT)0;
        }
    }
}

// ---------------------------------------------------------------------------
// dt GEMM + UD pack (XOR-swizzled LDS): dtraw = DT24 @ dtw_pad^T (K=32);
// UD = pack(bf16(softplus(dtraw+dtb)), XH).  BM=128, BN=64.
// ---------------------------------------------------------------------------
__global__ __launch_bounds__(256) void dtud_kernel(
    const ushortT* __restrict__ DT24, const ushortT* __restrict__ WDtf,
    const ushortT* __restrict__ WDtb,
    const float* __restrict__ dtbf, const float* __restrict__ dtbb,
    const ushortT* __restrict__ XH, uint32_t* __restrict__ UD, int rows)
{
    __shared__ ushortT As[128 * 32];
    __shared__ ushortT Ws[64 * 32];
    int dir = blockIdx.z;
    int bm = blockIdx.x * 128;
    int bn = blockIdx.y * 64;
    const ushortT* A = DT24 + (size_t)dir * rows * 32;
    const ushortT* W = dir ? WDtb : WDtf;
    const float* dtb = dir ? dtbb : dtbf;
    const ushortT* xh = XH + (size_t)dir * rows * DI_;
    uint32_t* ud = UD + (size_t)dir * rows * DI_;
    int tid = threadIdx.x, wave = tid >> 6, lane = tid & 63;
    int lrow = lane >> 2, lk = stage_sw(lane);
    int rsw = read_sw(lane);

    stage16(A + (size_t)(bm + wave * 16 + lrow) * 32 + lk, &As[wave * 16 * 32]);
    stage16(A + (size_t)(bm + 64 + wave * 16 + lrow) * 32 + lk, &As[(64 + wave * 16) * 32]);
    stage16(W + (size_t)(bn + wave * 16 + lrow) * 32 + lk, &Ws[wave * 16 * 32]);
    __syncthreads();

    f32x4 acc[2][4] = {};
    bf16x8 bfr[4];
#pragma unroll
    for (int ni = 0; ni < 4; ni++)
        bfr[ni] = *(bf16x8*)&Ws[(ni * 16 + (lane & 15)) * 32 + rsw];
#pragma unroll
    for (int mi = 0; mi < 2; mi++) {
        bf16x8 af = *(bf16x8*)&As[(wave * 32 + mi * 16 + (lane & 15)) * 32 + rsw];
#pragma unroll
        for (int ni = 0; ni < 4; ni++)
            acc[mi][ni] = __builtin_amdgcn_mfma_f32_16x16x32_bf16(
                af, bfr[ni], acc[mi][ni], 0, 0, 0);
    }
#pragma unroll
    for (int ni = 0; ni < 4; ni++) {
        int d = bn + ni * 16 + (lane & 15);
        float bias = dtb[d];
#pragma unroll
        for (int mi = 0; mi < 2; mi++) {
            int rb = bm + wave * 32 + mi * 16 + (lane >> 4) * 4;
#pragma unroll
            for (int r = 0; r < 4; r++) {
                int row = rb + r;
                float dt = softplus_f(acc[mi][ni][r] + bias);
                float u = bf2f(xh[(size_t)row * DI_ + d]);
                ud[(size_t)row * DI_ + d] =
                    ((uint32_t)f2bf(dt) << 16) | (uint32_t)f2bf(u);
            }
        }
    }
}

// ---------------------------------------------------------------------------
// Chunked selective scan, phase 1: 8-wide distance-1 prefetch;
// stages only B cols; publishes packed bf16 (dec<<16 | hs1).
// A=-(n+1)*a1 fast path.
// ---------------------------------------------------------------------------
__global__ __launch_bounds__(256) void scan1_kernel(
    const uint32_t* __restrict__ UD,
    const float* __restrict__ dbcf, const float* __restrict__ dbcb,
    const float* __restrict__ alogf, const float* __restrict__ alogb,
    uint32_t* __restrict__ SD, int gB)
{
    int bid = blockIdx.x;
    int c = bid % NC_; bid /= NC_;
    int dchunk = bid % 3; bid /= 3;
    int b = bid % gB;
    int dir = bid / gB;
    int d = dchunk * 256 + threadIdx.x;

    const float* dbc  = dir ? dbcb : dbcf;
    const float* alog = dir ? alogb : alogf;

    float An[NS_];
#pragma unroll
    for (int n = 0; n < NS_; n++) An[n] = -__expf(alog[d * NS_ + n]);
    float a1 = An[0];
    bool pk = true;
#pragma unroll
    for (int n = 0; n < NS_; n++)
        pk = pk && (fabsf(An[n] - (float)(n + 1) * a1) <=
                    1e-3f * (float)(n + 1) * fabsf(a1) + 1e-6f);
    pk = (bool)__all((int)pk);

    __shared__ float sB[LC_ * 16];
    int rb = b * LN_ + c * LC_;
    int jb = c * LC_;
    {
        int row = threadIdx.x >> 2, c4 = (threadIdx.x & 3) * 4;
        *(float4*)&sB[row * 16 + c4] =
            *(const float4*)(dbc + (size_t)(rb + row) * NDBCP + RDT_ + c4);
    }
    __syncthreads();

    float h[NS_];
#pragma unroll
    for (int n = 0; n < NS_; n++) h[n] = 0.0f;
    float S = 0.0f;
    const uint32_t* udp = UD + (size_t)((dir * gB + b) * LN_ + jb) * DI_ + d;

    if (pk) {
        uint32_t ud8[8];
#pragma unroll
        for (int i = 0; i < 8; i++) ud8[i] = udp[i * DI_];
        for (int lt = 0; lt < LC_; lt += 8) {
            uint32_t cur[8];
#pragma unroll
            for (int i = 0; i < 8; i++) cur[i] = ud8[i];
            if (lt + 8 < LC_) {
#pragma unroll
                for (int i = 0; i < 8; i++) ud8[i] = udp[(lt + 8 + i) * DI_];
            }
#pragma unroll
            for (int i = 0; i < 8; i++) {
                int lr = lt + i;
                const float4* Bp4 = (const float4*)&sB[lr * 16];
                float4 B0 = Bp4[0], B1 = Bp4[1], B2 = Bp4[2], B3 = Bp4[3];
                float Bv[NS_] = {B0.x, B0.y, B0.z, B0.w, B1.x, B1.y, B1.z, B1.w,
                                 B2.x, B2.y, B2.z, B2.w, B3.x, B3.y, B3.z, B3.w};
                float u = bf2f((ushortT)(cur[i] & 0xffffu));
                float dt = bf2f((ushortT)(cur[i] >> 16));
                S += dt;
                float du = dt * u;
                float q1 = __expf(dt * a1);
                float q2 = q1 * q1, q4 = q2 * q2, q8 = q4 * q4;
                float p2 = q2, p3 = q2 * q1, p5 = q4 * q1, p6 = q4 * q2, p7 = q4 * p3;
                float pw[NS_] = {q1, p2, p3, q4, p5, p6, p7, q8,
                                 q8 * q1, q8 * p2, q8 * p3, q8 * q4,
                                 q8 * p5, q8 * p6, q8 * p7, q8 * q8};
#pragma unroll
                for (int n = 0; n < NS_; n++)
                    h[n] = fmaf(h[n], pw[n], du * Bv[n]);
            }
        }
        float q1 = __expf(S * a1);
        float q2 = q1 * q1, q4 = q2 * q2, q8 = q4 * q4;
        float p2 = q2, p3 = q2 * q1, p5 = q4 * q1, p6 = q4 * q2, p7 = q4 * p3;
        float pw[NS_] = {q1, p2, p3, q4, p5, p6, p7, q8,
                         q8 * q1, q8 * p2, q8 * p3, q8 * q4,
                         q8 * p5, q8 * p6, q8 * p7, q8 * q8};
        int si = (((dir * gB + b) * NC_ + c) * DI_ + d) * NS_;
#pragma unroll
        for (int n = 0; n < NS_; n++)
            SD[si + n] = ((uint32_t)f2bf(pw[n]) << 16) | (uint32_t)f2bf(h[n]);
    } else {
        for (int lr = 0; lr < LC_; lr++) {
            const float* rowp = &sB[lr * 16];
            uint32_t udv = udp[lr * DI_];
            float u = bf2f((ushortT)(udv & 0xffffu));
            float dt = bf2f((ushortT)(udv >> 16));
            S += dt;
            float du = dt * u;
#pragma unroll
            for (int n = 0; n < NS_; n++)
                h[n] = fmaf(h[n], __expf(dt * An[n]), du * rowp[n]);
        }
        int si = (((dir * gB + b) * NC_ + c) * DI_ + d) * NS_;
#pragma unroll
        for (int n = 0; n < NS_; n++)
            SD[si + n] = ((uint32_t)f2bf(__expf(An[n] * S)) << 16) |
                         (uint32_t)f2bf(h[n]);
    }
}

__global__ __launch_bounds__(256) void scan2_kernel(
    const uint32_t* __restrict__ SD, ushortT* __restrict__ hin, int gB)
{
    int e = blockIdx.x * 256 + threadIdx.x;
    int n = e & 15; int e2 = e >> 4;
    int d = e2 % DI_; e2 /= DI_;
    int b = e2 % gB; int dir = e2 / gB;
    int base = (((dir * gB + b) * NC_) * DI_ + d) * NS_ + n;
    float h = 0.0f;
    const int cs = DI_ * NS_;
    for (int c = 0; c < NC_; c++) {
        int idx = base + c * cs;
        uint32_t sd = SD[idx];
        hin[idx] = f2bf(h);
        h = fmaf(h, bf2f((ushortT)(sd >> 16)), bf2f((ushortT)(sd & 0xffffu)));
    }
}

// Phase 3: 8-wide distance-1 prefetch (UD + z), single-buffer (register-
// allocation-robust R8 form); h seeded from bf16 hin.
__global__ __launch_bounds__(256) void scan3_kernel(
    const uint32_t* __restrict__ UD, const ushortT* __restrict__ XZ,
    const float* __restrict__ dbcf, const float* __restrict__ dbcb,
    const float* __restrict__ alogf, const float* __restrict__ dvf,
    const float* __restrict__ alogb, const float* __restrict__ dvb,
    const ushortT* __restrict__ hin,
    ushortT* __restrict__ yf, ushortT* __restrict__ yb, int gB)
{
    int bid = blockIdx.x;
    int c = bid % NC_; bid /= NC_;
    int dchunk = bid % 3; bid /= 3;
    int b = bid % gB;
    int dir = bid / gB;
    int d = dchunk * 256 + threadIdx.x;

    const float* dbc  = dir ? dbcb : dbcf;
    const float* alog = dir ? alogb : alogf;
    float Dd          = (dir ? dvb : dvf)[d];
    ushortT* y        = dir ? yb : yf;

    float An[NS_];
#pragma unroll
    for (int n = 0; n < NS_; n++) An[n] = -__expf(alog[d * NS_ + n]);
    float a1 = An[0];
    bool pk = true;
#pragma unroll
    for (int n = 0; n < NS_; n++)
        pk = pk && (fabsf(An[n] - (float)(n + 1) * a1) <=
                    1e-3f * (float)(n + 1) * fabsf(a1) + 1e-6f);
    pk = (bool)__all((int)pk);

    __shared__ float sBC[LC_ * 32];
    int rb = b * LN_ + c * LC_;
    int jb = c * LC_;
#pragma unroll
    for (int i = 0; i < 2; i++) {
        int idx = threadIdx.x + 256 * i;
        int row = idx >> 3, c4 = (idx & 7) * 4;
        *(float4*)&sBC[row * 32 + c4] =
            *(const float4*)(dbc + (size_t)(rb + row) * NDBCP + RDT_ + c4);
    }
    __syncthreads();

    int si = (((dir * gB + b) * NC_ + c) * DI_ + d) * NS_;
    float h[NS_];
#pragma unroll
    for (int n = 0; n < NS_; n++) h[n] = bf2f(hin[si + n]);
    const uint32_t* udp = UD + (size_t)((dir * gB + b) * LN_ + jb) * DI_ + d;

    if (pk) {
        uint32_t ud8[8];
        ushortT z8[8];
#pragma unroll
        for (int i = 0; i < 8; i++) {
            ud8[i] = udp[i * DI_];
            int j = jb + i;
            int lo = dir ? (LN_ - 1 - j) : j;
            z8[i] = XZ[(size_t)(b * LN_ + lo) * (2 * DI_) + DI_ + d];
        }
        for (int lt = 0; lt < LC_; lt += 8) {
            uint32_t cud[8];
            ushortT cz[8];
#pragma unroll
            for (int i = 0; i < 8; i++) { cud[i] = ud8[i]; cz[i] = z8[i]; }
            if (lt + 8 < LC_) {
#pragma unroll
                for (int i = 0; i < 8; i++) {
                    ud8[i] = udp[(lt + 8 + i) * DI_];
                    int j = jb + lt + 8 + i;
                    int lo = dir ? (LN_ - 1 - j) : j;
                    z8[i] = XZ[(size_t)(b * LN_ + lo) * (2 * DI_) + DI_ + d];
                }
            }
#pragma unroll
            for (int i = 0; i < 8; i++) {
                int lr = lt + i;
                const float4* rp4 = (const float4*)&sBC[lr * 32];
                float4 B0 = rp4[0], B1 = rp4[1], B2 = rp4[2], B3 = rp4[3];
                float4 C0 = rp4[4], C1 = rp4[5], C2 = rp4[6], C3 = rp4[7];
                float Bv[NS_] = {B0.x, B0.y, B0.z, B0.w, B1.x, B1.y, B1.z, B1.w,
                                 B2.x, B2.y, B2.z, B2.w, B3.x, B3.y, B3.z, B3.w};
                float Cw[NS_] = {C0.x, C0.y, C0.z, C0.w, C1.x, C1.y, C1.z, C1.w,
                                 C2.x, C2.y, C2.z, C2.w, C3.x, C3.y, C3.z, C3.w};
                float u = bf2f((ushortT)(cud[i] & 0xffffu));
                float dt = bf2f((ushortT)(cud[i] >> 16));
                float du = dt * u;
                float q1 = __expf(dt * a1);
                float q2 = q1 * q1, q4 = q2 * q2, q8 = q4 * q4;
                float p2 = q2, p3 = q2 * q1, p5 = q4 * q1, p6 = q4 * q2, p7 = q4 * p3;
                float pw[NS_] = {q1, p2, p3, q4, p5, p6, p7, q8,
                                 q8 * q1, q8 * p2, q8 * p3, q8 * q4,
                                 q8 * p5, q8 * p6, q8 * p7, q8 * q8};
                float y0 = 0.f, y1 = 0.f, y2 = 0.f, y3 = 0.f;
#pragma unroll
                for (int n = 0; n < NS_; n += 4) {
                    h[n + 0] = fmaf(h[n + 0], pw[n + 0], du * Bv[n + 0]);
                    h[n + 1] = fmaf(h[n + 1], pw[n + 1], du * Bv[n + 1]);
                    h[n + 2] = fmaf(h[n + 2], pw[n + 2], du * Bv[n + 2]);
                    h[n + 3] = fmaf(h[n + 3], pw[n + 3], du * Bv[n + 3]);
                    y0 = fmaf(h[n + 0], Cw[n + 0], y0);
                    y1 = fmaf(h[n + 1], Cw[n + 1], y1);
                    y2 = fmaf(h[n + 2], Cw[n + 2], y2);
                    y3 = fmaf(h[n + 3], Cw[n + 3], y3);
                }
                float yv = ((y0 + y1) + (y2 + y3)) + u * Dd;
                int j = jb + lr;
                int lo = dir ? (LN_ - 1 - j) : j;
                float z = bf2f(cz[i]);
                y[(b * LN_ + lo) * DI_ + d] = f2bf(yv * silu_f(z));
            }
        }
    } else {
        for (int lr = 0; lr < LC_; lr++) {
            const float* rowp = &sBC[lr * 32];
            uint32_t ud = udp[lr * DI_];
            float u = bf2f((ushortT)(ud & 0xffffu));
            float dt = bf2f((ushortT)(ud >> 16));
            float du = dt * u;
            float y0 = 0.f, y1 = 0.f, y2 = 0.f, y3 = 0.f;
#pragma unroll
            for (int n = 0; n < NS_; n += 4) {
                h[n + 0] = fmaf(h[n + 0], __expf(dt * An[n + 0]), du * rowp[n + 0]);
                h[n + 1] = fmaf(h[n + 1], __expf(dt * An[n + 1]), du * rowp[n + 1]);
                h[n + 2] = fmaf(h[n + 2], __expf(dt * An[n + 2]), du * rowp[n + 2]);
                h[n + 3] = fmaf(h[n + 3], __expf(dt * An[n + 3]), du * rowp[n + 3]);
                y0 = fmaf(h[n + 0], rowp[16 + n + 0], y0);
                y1 = fmaf(h[n + 1], rowp[16 + n + 1], y1);
                y2 = fmaf(h[n + 2], rowp[16 + n + 2], y2);
                y3 = fmaf(h[n + 3], rowp[16 + n + 3], y3);
            }
            float yv = ((y0 + y1) + (y2 + y3)) + u * Dd;
            int j = jb + lr;
            int lo = dir ? (LN_ - 1 - j) : j;
            float z = bf2f(XZ[(size_t)(b * LN_ + lo) * (2 * DI_) + DI_ + d]);
            y[(b * LN_ + lo) * DI_ + d] = f2bf(yv * silu_f(z));
        }
    }
}

// ---------------------------------------------------------------------------
// Host launcher.
// ---------------------------------------------------------------------------
extern "C" void kernel_launch(void* const* d_in, const int* in_sizes, int n_in,
                              void* d_out, int out_size, void* d_ws, size_t ws_size,
                              hipStream_t stream)
{
    const float* x         = (const float*)d_in[0];
    const float* ln_w      = (const float*)d_in[1];
    const float* ln_b      = (const float*)d_in[2];
    const float* in_proj_w = (const float*)d_in[3];
    const float* out_proj_w= (const float*)d_in[4];
    const float* conv_wf   = (const float*)d_in[5];
    const float* conv_bf   = (const float*)d_in[6];
    const float* xproj_f   = (const float*)d_in[7];
    const float* dt_wf     = (const float*)d_in[8];
    const float* dt_bf     = (const float*)d_in[9];
    const float* alog_f    = (const float*)d_in[10];
    const float* dv_f      = (const float*)d_in[11];
    const float* conv_wb   = (const float*)d_in[12];
    const float* conv_bb   = (const float*)d_in[13];
    const float* xproj_b   = (const float*)d_in[14];
    const float* dt_wb     = (const float*)d_in[15];
    const float* dt_bb     = (const float*)d_in[16];
    const float* alog_b    = (const float*)d_in[17];
    const float* dv_b      = (const float*)d_in[18];
    float* outp = (float*)d_out;

    const int n_w1 = 2 * DI_ * DM_;
    const int n_w2 = DM_ * DI_;
    const int n_wx = NDBCP * DI_;
    const int n_wd = DI_ * 32;

    uint8_t* base = (uint8_t*)d_ws;
    size_t off = 0;
    auto alloc = [&](size_t nbytes) {
        uint8_t* r = base + off;
        off = (off + nbytes + 255) & ~(size_t)255;
        return r;
    };
    ushortT* WbIn  = (ushortT*)alloc((size_t)n_w1 * 2);
    ushortT* WbOut = (ushortT*)alloc((size_t)n_w2 * 2);
    ushortT* WbXf  = (ushortT*)alloc((size_t)n_wx * 2);
    ushortT* WbXb  = (ushortT*)alloc((size_t)n_wx * 2);
    ushortT* WbDtf = (ushortT*)alloc((size_t)n_wd * 2);
    ushortT* WbDtb = (ushortT*)alloc((size_t)n_wd * 2);
    size_t fixed_bytes = off;

    size_t per_b_bytes = 21ull * 1024 * 1024;
    int g = BN_;
    while (g > 1 && fixed_bytes + (size_t)g * per_b_bytes + (1ull << 20) > ws_size) g >>= 1;

    wconv_kernel<<<(n_w1 + n_w2 + 2 * n_wx + 2 * n_wd + 255) / 256, 256, 0, stream>>>(
        in_proj_w, n_w1, out_proj_w, n_w2, xproj_f, xproj_b, dt_wf, dt_wb,
        WbIn, WbOut, WbXf, WbXb, WbDtf, WbDtb);

    for (int b0 = 0; b0 < BN_; b0 += g) {
        int rows = g * LN_;
        off = fixed_bytes;
        ushortT* XNb  = (ushortT*)alloc((size_t)rows * DM_ * 2);
        ushortT* XZ   = (ushortT*)alloc((size_t)rows * 2 * DI_ * 2);
        ushortT* XH   = (ushortT*)alloc((size_t)2 * rows * DI_ * 2);
        float* DBCf   = (float*)alloc((size_t)rows * NDBCP * 4);
        float* DBCb   = (float*)alloc((size_t)rows * NDBCP * 4);
        ushortT* DT24 = (ushortT*)alloc((size_t)2 * rows * 32 * 2);
        uint32_t* UD  = (uint32_t*)alloc((size_t)2 * rows * DI_ * 4);
        size_t st_n   = (size_t)2 * g * NC_ * DI_ * NS_;
        uint32_t* SD  = (uint32_t*)alloc(st_n * 4);
        ushortT* HIN  = (ushortT*)alloc(st_n * 2);
        ushortT* Yf   = (ushortT*)alloc((size_t)rows * DI_ * 2);
        ushortT* Yb   = (ushortT*)alloc((size_t)rows * DI_ * 2);
        int row0 = b0 * LN_;

        ln_kernel<<<rows / 4, 256, 0, stream>>>(x, ln_w, ln_b, XNb, row0, rows);

        gemm_mfma<128, 128, 2, 2, false, false, true>
            <<<dim3(rows / 128, (2 * DI_) / 128), 256, 0, stream>>>(
            XNb, nullptr, WbIn, nullptr, XZ, rows, 2 * DI_, DM_);

        conv_kernel<<<(2 * rows * (DI_ / 8)) / 256, 256, 0, stream>>>(
            XZ, conv_wf, conv_bf, conv_wb, conv_bb, XH, g);

        xproj_mfma<<<2 * (rows / 64), 256, 0, stream>>>(
            XH, WbXf, WbXb, DBCf, DBCb, DT24, rows / 64);

        dtud_kernel<<<dim3(rows / 128, DI_ / 64, 2), 256, 0, stream>>>(
            DT24, WbDtf, WbDtb, dt_bf, dt_bb, XH, UD, rows);

        scan1_kernel<<<2 * g * 3 * NC_, 256, 0, stream>>>(
            UD, DBCf, DBCb, alog_f, alog_b, SD, g);

        scan2_kernel<<<(2 * g * DI_ * NS_) / 256, 256, 0, stream>>>(SD, HIN, g);

        scan3_kernel<<<2 * g * 3 * NC_, 256, 0, stream>>>(
            UD, XZ, DBCf, DBCb, alog_f, dv_f, alog_b, dv_b,
            HIN, Yf, Yb, g);

        gemm_mfma<64, 128, 1, 4, true, true, false>
            <<<dim3(rows / 64, DM_ / 128), 256, 0, stream>>>(
            Yf, Yb, WbOut, x + (size_t)row0 * DM_,
            outp + (size_t)row0 * DM_, rows, DM_, DI_);
    }
}

// Round 14
// 421.493 us; speedup vs baseline: 1.3640x; 1.1515x over previous
//
#include <hip/hip_runtime.h>
#include <cstdint>
#include <cstddef>

// Problem constants
#define BN_   16
#define LN_   1024
#define DM_   384
#define DI_   768
#define NS_   16
#define RDT_  24
#define NDBC_ 56
#define NDBCP 64     // padded dbc stride
#define NC_   16
#define LC_   64

typedef unsigned short ushortT;
typedef short bf16x8 __attribute__((ext_vector_type(8)));
typedef float f32x4 __attribute__((ext_vector_type(4)));

typedef __attribute__((address_space(3))) uint32_t lds_u32_t;
typedef __attribute__((address_space(1))) const uint32_t glb_u32_t;

static __device__ __forceinline__ void stage16(const void* g, void* lds) {
    __builtin_amdgcn_global_load_lds(
        (glb_u32_t*)(uintptr_t)g,
        (lds_u32_t*)(uint32_t)(uintptr_t)lds,
        16, 0, 0);
}

// XOR-swizzle helpers for 16B granules in 64B rows (kills 8-way ds_read_b128
// bank conflicts -> free 2-way). Stage: lane l sources global granule
// (l&3)^((l>>3)&3). Read: fragment granule q at row m lives at q^((m>>1)&3).
static __device__ __forceinline__ int stage_sw(int lane) {
    return ((lane & 3) ^ ((lane >> 3) & 3)) * 8;   // ushort offset
}
static __device__ __forceinline__ int read_sw(int lane) {
    return (((lane >> 4) ^ (((lane & 15) >> 1) & 3)) * 8);  // ushort offset
}

static __device__ __forceinline__ float silu_f(float x) {
    return x / (1.0f + __expf(-x));
}
// fast softplus: ln(1+e^s) = max(s,0) + ln(1+e^-|s|)
static __device__ __forceinline__ float softplus_f(float s) {
    return fmaxf(s, 0.0f) + __logf(1.0f + __expf(-fabsf(s)));
}
static __device__ __forceinline__ ushortT f2bf(float f) {
    union { float f; uint32_t u; } v; v.f = f;
    uint32_t u = v.u;
    uint32_t r = u + 0x7fffu + ((u >> 16) & 1u);
    return (ushortT)(r >> 16);
}
static __device__ __forceinline__ float bf2f(ushortT b) {
    union { uint32_t u; float f; } v; v.u = ((uint32_t)b) << 16;
    return v.f;
}

// ---------------------------------------------------------------------------
// Weight conversions: in_proj/out_proj fp32->bf16; xproj bf16 padded to 64
// rows; dt_w bf16 padded to 32 cols (24..31 zero).
// ---------------------------------------------------------------------------
__global__ __launch_bounds__(256) void wconv_kernel(
    const float* __restrict__ w1, int n1, const float* __restrict__ w2, int n2,
    const float* __restrict__ xwf, const float* __restrict__ xwb,
    const float* __restrict__ dwf, const float* __restrict__ dwb,
    ushortT* __restrict__ o1, ushortT* __restrict__ o2,
    ushortT* __restrict__ oxf, ushortT* __restrict__ oxb,
    ushortT* __restrict__ odf, ushortT* __restrict__ odb)
{
    int i = blockIdx.x * 256 + threadIdx.x;
    if (i < n1) { o1[i] = f2bf(w1[i]); return; }
    i -= n1;
    if (i < n2) { o2[i] = f2bf(w2[i]); return; }
    i -= n2;
    const int nx = NDBCP * DI_;
    if (i < 2 * nx) {
        int which = i >= nx;
        int j = which ? (i - nx) : i;
        int row = j / DI_;
        const float* src = which ? xwb : xwf;
        ushortT* dst = which ? oxb : oxf;
        dst[j] = (row < NDBC_) ? f2bf(src[j]) : (ushortT)0;
        return;
    }
    i -= 2 * nx;
    const int nd = DI_ * 32;
    if (i < 2 * nd) {
        int which = i >= nd;
        int j = which ? (i - nd) : i;
        int row = j >> 5, col = j & 31;
        const float* src = which ? dwb : dwf;
        ushortT* dst = which ? odb : odf;
        dst[j] = (col < RDT_) ? f2bf(src[row * RDT_ + col]) : (ushortT)0;
    }
}

// ---------------------------------------------------------------------------
// LayerNorm: one wave per row of 384; block = 4 rows. Writes bf16.
// ---------------------------------------------------------------------------
__global__ __launch_bounds__(256) void ln_kernel(
    const float* __restrict__ x, const float* __restrict__ w,
    const float* __restrict__ b, ushortT* __restrict__ xn,
    int row0, int nrows)
{
    int r = blockIdx.x * 4 + (threadIdx.x >> 6);
    if (r >= nrows) return;
    int lane = threadIdx.x & 63;
    const float* xr = x + (size_t)(row0 + r) * DM_;
    float v[6];
    float s = 0.0f;
#pragma unroll
    for (int i = 0; i < 6; i++) { v[i] = xr[lane + 64 * i]; s += v[i]; }
#pragma unroll
    for (int o = 32; o > 0; o >>= 1) s += __shfl_down(s, o, 64);
    s = __shfl(s, 0, 64);
    float mu = s * (1.0f / DM_);
    float q = 0.0f;
#pragma unroll
    for (int i = 0; i < 6; i++) { float d = v[i] - mu; q += d * d; }
#pragma unroll
    for (int o = 32; o > 0; o >>= 1) q += __shfl_down(q, o, 64);
    q = __shfl(q, 0, 64);
    float rstd = rsqrtf(q * (1.0f / DM_) + 1e-5f);
    ushortT* outp = xn + (size_t)r * DM_;
#pragma unroll
    for (int i = 0; i < 6; i++) {
        int c = lane + 64 * i;
        outp[c] = f2bf((v[i] - mu) * rstd * w[c] + b[c]);
    }
}

// ---------------------------------------------------------------------------
// bf16 MFMA GEMM (m97-style, XOR-swizzled LDS): C = [Aa | Ab] * W^T (+ R)
// OB: write bf16 output (XZ) instead of fp32.
// ---------------------------------------------------------------------------
template <int BM, int BN, int WR, int WC, bool CAT, bool RES, bool OB>
__global__ __launch_bounds__(256) void gemm_mfma(
    const ushortT* __restrict__ Aa, const ushortT* __restrict__ Ab_,
    const ushortT* __restrict__ W, const float* __restrict__ R,
    void* __restrict__ Cv, int M, int N, int Khalf)
{
    constexpr int WTM = BM / WR;
    constexpr int WTN = BN / WC;
    constexpr int FM = WTM / 16;
    constexpr int FN = WTN / 16;
    __shared__ ushortT As[BM * 32];
    __shared__ ushortT Ws[BN * 32];
    int tid = threadIdx.x;
    int bm = blockIdx.x * BM, bn = blockIdx.y * BN;
    int wave = tid >> 6, lane = tid & 63;
    int wm = wave % WR, wn = wave / WR;
    f32x4 acc[FM][FN] = {};
    int Ktot = CAT ? 2 * Khalf : Khalf;
    int lrow = lane >> 2;
    int lk = stage_sw(lane);

    for (int k0 = 0; k0 < Ktot; k0 += 32) {
        const ushortT* Asrc = (!CAT || k0 < Khalf) ? Aa : Ab_;
        int ka = (!CAT || k0 < Khalf) ? k0 : (k0 - Khalf);
        __syncthreads();
#pragma unroll
        for (int c = 0; c < BM / 64; c++) {
            int ch = c * 4 + wave;
            int row = ch * 16 + lrow;
            stage16(Asrc + (size_t)(bm + row) * Khalf + ka + lk, &As[ch * 16 * 32]);
        }
#pragma unroll
        for (int c = 0; c < BN / 64; c++) {
            int ch = c * 4 + wave;
            int row = ch * 16 + lrow;
            stage16(W + (size_t)(bn + row) * Khalf + ka + lk, &Ws[ch * 16 * 32]);
        }
        __syncthreads();
        int rsw = read_sw(lane);
        int mb = (wm * WTM + (lane & 15)) * 32 + rsw;
        int nb = (wn * WTN + (lane & 15)) * 32 + rsw;
        bf16x8 af[FM], bfr[FN];
#pragma unroll
        for (int mi = 0; mi < FM; mi++) af[mi] = *(bf16x8*)&As[mb + mi * 16 * 32];
#pragma unroll
        for (int ni = 0; ni < FN; ni++) bfr[ni] = *(bf16x8*)&Ws[nb + ni * 16 * 32];
#pragma unroll
        for (int mi = 0; mi < FM; mi++)
#pragma unroll
            for (int ni = 0; ni < FN; ni++)
                acc[mi][ni] = __builtin_amdgcn_mfma_f32_16x16x32_bf16(
                    af[mi], bfr[ni], acc[mi][ni], 0, 0, 0);
    }

#pragma unroll
    for (int mi = 0; mi < FM; mi++) {
        int row = bm + wm * WTM + 16 * mi + (lane >> 4) * 4;
#pragma unroll
        for (int ni = 0; ni < FN; ni++) {
            int col = bn + wn * WTN + 16 * ni + (lane & 15);
#pragma unroll
            for (int r = 0; r < 4; r++) {
                size_t o = (size_t)(row + r) * N + col;
                float v = acc[mi][ni][r];
                if (RES) v += R[o];
                if (OB) ((ushortT*)Cv)[o] = f2bf(v);
                else    ((float*)Cv)[o] = v;
            }
        }
    }
}

// ---------------------------------------------------------------------------
// Causal depthwise conv (K=4) + silu: bf16 XZ -> bf16 XH, 8 ch/thread.
// XH layout: [dir][gB*LN][DI] in j-space.
// ---------------------------------------------------------------------------
__global__ __launch_bounds__(256) void conv_kernel(
    const ushortT* __restrict__ XZ,
    const float* __restrict__ wf, const float* __restrict__ bf,
    const float* __restrict__ wb, const float* __restrict__ bb,
    ushortT* __restrict__ XH, int gB)
{
    const int D8 = DI_ / 8;  // 96
    int idx = blockIdx.x * 256 + threadIdx.x;
    int perdir = gB * LN_ * D8;
    int dir = 0;
    if (idx >= perdir) { idx -= perdir; dir = 1; }
    int d8 = idx % D8;
    int l = (idx / D8) & (LN_ - 1);
    int b = idx / (D8 * LN_);
    int d = d8 * 8;
    const float* cw = (dir ? wb : wf) + d * 4;
    const float* cb = (dir ? bb : bf) + d;

    float xv[4][8];
#pragma unroll
    for (int k = 0; k < 4; k++) {
        int j = l - 3 + k;
        if (j < 0) {
#pragma unroll
            for (int c = 0; c < 8; c++) xv[k][c] = 0.0f;
        } else {
            int ls = dir ? (LN_ - 1 - j) : j;
            ushort4 v = *(const ushort4*)(XZ + (size_t)(b * LN_ + ls) * (2 * DI_) + d);
            ushort4 v2 = *(const ushort4*)(XZ + (size_t)(b * LN_ + ls) * (2 * DI_) + d + 4);
            xv[k][0] = bf2f(v.x);  xv[k][1] = bf2f(v.y);
            xv[k][2] = bf2f(v.z);  xv[k][3] = bf2f(v.w);
            xv[k][4] = bf2f(v2.x); xv[k][5] = bf2f(v2.y);
            xv[k][6] = bf2f(v2.z); xv[k][7] = bf2f(v2.w);
        }
    }
    ushortT out[8];
#pragma unroll
    for (int c = 0; c < 8; c++) {
        float4 w4 = *(const float4*)(cw + c * 4);
        float s = cb[c];
        s = fmaf(xv[0][c], w4.x, s);
        s = fmaf(xv[1][c], w4.y, s);
        s = fmaf(xv[2][c], w4.z, s);
        s = fmaf(xv[3][c], w4.w, s);
        out[c] = f2bf(silu_f(s));
    }
    ushortT* op = XH + ((size_t)dir * gB * LN_ + (size_t)(b * LN_ + l)) * DI_ + d;
    *(ushort4*)(op + 0) = make_ushort4(out[0], out[1], out[2], out[3]);
    *(ushort4*)(op + 4) = make_ushort4(out[4], out[5], out[6], out[7]);
}

// ---------------------------------------------------------------------------
// xproj MFMA (XOR-swizzled LDS): C[dir][M x 64] = XH * Wpad^T; also writes
// DT24 (bf16 dt-cols, zero-padded to 32) for the dt GEMM.
// ---------------------------------------------------------------------------
__global__ __launch_bounds__(256) void xproj_mfma(
    const ushortT* __restrict__ XH, const ushortT* __restrict__ Wf,
    const ushortT* __restrict__ Wb, float* __restrict__ Cf,
    float* __restrict__ Cb, ushortT* __restrict__ DT24, int mblocksPerDir)
{
    __shared__ ushortT As[64 * 32];
    __shared__ ushortT Ws[64 * 32];
    int blk = blockIdx.x;
    int dir = blk >= mblocksPerDir;
    const ushortT* W = dir ? Wb : Wf;
    float* C = dir ? Cb : Cf;
    int bmG = blk * 64;
    int bmC = (blk - dir * mblocksPerDir) * 64;
    int tid = threadIdx.x, wave = tid >> 6, lane = tid & 63;
    f32x4 acc[4] = {};
    int lrow = lane >> 2;
    int lk = stage_sw(lane);
    int rsw = read_sw(lane);

    for (int k0 = 0; k0 < DI_; k0 += 32) {
        __syncthreads();
        stage16(XH + (size_t)(bmG + wave * 16 + lrow) * DI_ + k0 + lk, &As[wave * 16 * 32]);
        stage16(W + (size_t)(wave * 16 + lrow) * DI_ + k0 + lk, &Ws[wave * 16 * 32]);
        __syncthreads();
        bf16x8 bfr = *(bf16x8*)&Ws[(wave * 16 + (lane & 15)) * 32 + rsw];
#pragma unroll
        for (int mi = 0; mi < 4; mi++) {
            bf16x8 af = *(bf16x8*)&As[(mi * 16 + (lane & 15)) * 32 + rsw];
            acc[mi] = __builtin_amdgcn_mfma_f32_16x16x32_bf16(af, bfr, acc[mi], 0, 0, 0);
        }
    }
#pragma unroll
    for (int mi = 0; mi < 4; mi++) {
        int row = bmC + 16 * mi + (lane >> 4) * 4;
        int col = wave * 16 + (lane & 15);
#pragma unroll
        for (int r = 0; r < 4; r++)
            C[(size_t)(row + r) * NDBCP + col] = acc[mi][r];
    }
    if (wave < 2) {
        ushortT* dtp = DT24 + (size_t)dir * (size_t)(mblocksPerDir * 64) * 32;
        int col = wave * 16 + (lane & 15);
#pragma unroll
        for (int mi = 0; mi < 4; mi++) {
            int row = bmC + 16 * mi + (lane >> 4) * 4;
#pragma unroll
            for (int r = 0; r < 4; r++)
                dtp[(size_t)(row + r) * 32 + col] =
                    (col < RDT_) ? f2bf(acc[mi][r]) : (ushortT)0;
        }
    }
}

// ---------------------------------------------------------------------------
// dt GEMM + UD pack (XOR-swizzled LDS): dtraw = DT24 @ dtw_pad^T (K=32);
// UD = pack(bf16(softplus(dtraw+dtb)), XH).  BM=128, BN=64.
// ---------------------------------------------------------------------------
__global__ __launch_bounds__(256) void dtud_kernel(
    const ushortT* __restrict__ DT24, const ushortT* __restrict__ WDtf,
    const ushortT* __restrict__ WDtb,
    const float* __restrict__ dtbf, const float* __restrict__ dtbb,
    const ushortT* __restrict__ XH, uint32_t* __restrict__ UD, int rows)
{
    __shared__ ushortT As[128 * 32];
    __shared__ ushortT Ws[64 * 32];
    int dir = blockIdx.z;
    int bm = blockIdx.x * 128;
    int bn = blockIdx.y * 64;
    const ushortT* A = DT24 + (size_t)dir * rows * 32;
    const ushortT* W = dir ? WDtb : WDtf;
    const float* dtb = dir ? dtbb : dtbf;
    const ushortT* xh = XH + (size_t)dir * rows * DI_;
    uint32_t* ud = UD + (size_t)dir * rows * DI_;
    int tid = threadIdx.x, wave = tid >> 6, lane = tid & 63;
    int lrow = lane >> 2, lk = stage_sw(lane);
    int rsw = read_sw(lane);

    stage16(A + (size_t)(bm + wave * 16 + lrow) * 32 + lk, &As[wave * 16 * 32]);
    stage16(A + (size_t)(bm + 64 + wave * 16 + lrow) * 32 + lk, &As[(64 + wave * 16) * 32]);
    stage16(W + (size_t)(bn + wave * 16 + lrow) * 32 + lk, &Ws[wave * 16 * 32]);
    __syncthreads();

    f32x4 acc[2][4] = {};
    bf16x8 bfr[4];
#pragma unroll
    for (int ni = 0; ni < 4; ni++)
        bfr[ni] = *(bf16x8*)&Ws[(ni * 16 + (lane & 15)) * 32 + rsw];
#pragma unroll
    for (int mi = 0; mi < 2; mi++) {
        bf16x8 af = *(bf16x8*)&As[(wave * 32 + mi * 16 + (lane & 15)) * 32 + rsw];
#pragma unroll
        for (int ni = 0; ni < 4; ni++)
            acc[mi][ni] = __builtin_amdgcn_mfma_f32_16x16x32_bf16(
                af, bfr[ni], acc[mi][ni], 0, 0, 0);
    }
#pragma unroll
    for (int ni = 0; ni < 4; ni++) {
        int d = bn + ni * 16 + (lane & 15);
        float bias = dtb[d];
#pragma unroll
        for (int mi = 0; mi < 2; mi++) {
            int rb = bm + wave * 32 + mi * 16 + (lane >> 4) * 4;
#pragma unroll
            for (int r = 0; r < 4; r++) {
                int row = rb + r;
                float dt = softplus_f(acc[mi][ni][r] + bias);
                float u = bf2f(xh[(size_t)row * DI_ + d]);
                ud[(size_t)row * DI_ + d] =
                    ((uint32_t)f2bf(dt) << 16) | (uint32_t)f2bf(u);
            }
        }
    }
}

// ---------------------------------------------------------------------------
// Chunked selective scan, phase 1: 8-wide distance-1 prefetch;
// stages only B cols; publishes packed bf16 (dec<<16 | hs1).
// A=-(n+1)*a1 fast path.
// ---------------------------------------------------------------------------
__global__ __launch_bounds__(256) void scan1_kernel(
    const uint32_t* __restrict__ UD,
    const float* __restrict__ dbcf, const float* __restrict__ dbcb,
    const float* __restrict__ alogf, const float* __restrict__ alogb,
    uint32_t* __restrict__ SD, int gB)
{
    int bid = blockIdx.x;
    int c = bid % NC_; bid /= NC_;
    int dchunk = bid % 3; bid /= 3;
    int b = bid % gB;
    int dir = bid / gB;
    int d = dchunk * 256 + threadIdx.x;

    const float* dbc  = dir ? dbcb : dbcf;
    const float* alog = dir ? alogb : alogf;

    float An[NS_];
#pragma unroll
    for (int n = 0; n < NS_; n++) An[n] = -__expf(alog[d * NS_ + n]);
    float a1 = An[0];
    bool pk = true;
#pragma unroll
    for (int n = 0; n < NS_; n++)
        pk = pk && (fabsf(An[n] - (float)(n + 1) * a1) <=
                    1e-3f * (float)(n + 1) * fabsf(a1) + 1e-6f);
    pk = (bool)__all((int)pk);

    __shared__ float sB[LC_ * 16];
    int rb = b * LN_ + c * LC_;
    int jb = c * LC_;
    {
        int row = threadIdx.x >> 2, c4 = (threadIdx.x & 3) * 4;
        *(float4*)&sB[row * 16 + c4] =
            *(const float4*)(dbc + (size_t)(rb + row) * NDBCP + RDT_ + c4);
    }
    __syncthreads();

    float h[NS_];
#pragma unroll
    for (int n = 0; n < NS_; n++) h[n] = 0.0f;
    float S = 0.0f;
    const uint32_t* udp = UD + (size_t)((dir * gB + b) * LN_ + jb) * DI_ + d;

    if (pk) {
        uint32_t ud8[8];
#pragma unroll
        for (int i = 0; i < 8; i++) ud8[i] = udp[i * DI_];
        for (int lt = 0; lt < LC_; lt += 8) {
            uint32_t cur[8];
#pragma unroll
            for (int i = 0; i < 8; i++) cur[i] = ud8[i];
            if (lt + 8 < LC_) {
#pragma unroll
                for (int i = 0; i < 8; i++) ud8[i] = udp[(lt + 8 + i) * DI_];
            }
#pragma unroll
            for (int i = 0; i < 8; i++) {
                int lr = lt + i;
                const float4* Bp4 = (const float4*)&sB[lr * 16];
                float4 B0 = Bp4[0], B1 = Bp4[1], B2 = Bp4[2], B3 = Bp4[3];
                float Bv[NS_] = {B0.x, B0.y, B0.z, B0.w, B1.x, B1.y, B1.z, B1.w,
                                 B2.x, B2.y, B2.z, B2.w, B3.x, B3.y, B3.z, B3.w};
                float u = bf2f((ushortT)(cur[i] & 0xffffu));
                float dt = bf2f((ushortT)(cur[i] >> 16));
                S += dt;
                float du = dt * u;
                float q1 = __expf(dt * a1);
                float q2 = q1 * q1, q4 = q2 * q2, q8 = q4 * q4;
                float p2 = q2, p3 = q2 * q1, p5 = q4 * q1, p6 = q4 * q2, p7 = q4 * p3;
                float pw[NS_] = {q1, p2, p3, q4, p5, p6, p7, q8,
                                 q8 * q1, q8 * p2, q8 * p3, q8 * q4,
                                 q8 * p5, q8 * p6, q8 * p7, q8 * q8};
#pragma unroll
                for (int n = 0; n < NS_; n++)
                    h[n] = fmaf(h[n], pw[n], du * Bv[n]);
            }
        }
        float q1 = __expf(S * a1);
        float q2 = q1 * q1, q4 = q2 * q2, q8 = q4 * q4;
        float p2 = q2, p3 = q2 * q1, p5 = q4 * q1, p6 = q4 * q2, p7 = q4 * p3;
        float pw[NS_] = {q1, p2, p3, q4, p5, p6, p7, q8,
                         q8 * q1, q8 * p2, q8 * p3, q8 * q4,
                         q8 * p5, q8 * p6, q8 * p7, q8 * q8};
        int si = (((dir * gB + b) * NC_ + c) * DI_ + d) * NS_;
#pragma unroll
        for (int n = 0; n < NS_; n++)
            SD[si + n] = ((uint32_t)f2bf(pw[n]) << 16) | (uint32_t)f2bf(h[n]);
    } else {
        for (int lr = 0; lr < LC_; lr++) {
            const float* rowp = &sB[lr * 16];
            uint32_t udv = udp[lr * DI_];
            float u = bf2f((ushortT)(udv & 0xffffu));
            float dt = bf2f((ushortT)(udv >> 16));
            S += dt;
            float du = dt * u;
#pragma unroll
            for (int n = 0; n < NS_; n++)
                h[n] = fmaf(h[n], __expf(dt * An[n]), du * rowp[n]);
        }
        int si = (((dir * gB + b) * NC_ + c) * DI_ + d) * NS_;
#pragma unroll
        for (int n = 0; n < NS_; n++)
            SD[si + n] = ((uint32_t)f2bf(__expf(An[n] * S)) << 16) |
                         (uint32_t)f2bf(h[n]);
    }
}

__global__ __launch_bounds__(256) void scan2_kernel(
    const uint32_t* __restrict__ SD, ushortT* __restrict__ hin, int gB)
{
    int e = blockIdx.x * 256 + threadIdx.x;
    int n = e & 15; int e2 = e >> 4;
    int d = e2 % DI_; e2 /= DI_;
    int b = e2 % gB; int dir = e2 / gB;
    int base = (((dir * gB + b) * NC_) * DI_ + d) * NS_ + n;
    float h = 0.0f;
    const int cs = DI_ * NS_;
    for (int c = 0; c < NC_; c++) {
        int idx = base + c * cs;
        uint32_t sd = SD[idx];
        hin[idx] = f2bf(h);
        h = fmaf(h, bf2f((ushortT)(sd >> 16)), bf2f((ushortT)(sd & 0xffffu)));
    }
}

// Phase 3: 8-wide distance-1 prefetch (UD + z), single-buffer (register-
// allocation-robust R8 form); h seeded from bf16 hin.
__global__ __launch_bounds__(256) void scan3_kernel(
    const uint32_t* __restrict__ UD, const ushortT* __restrict__ XZ,
    const float* __restrict__ dbcf, const float* __restrict__ dbcb,
    const float* __restrict__ alogf, const float* __restrict__ dvf,
    const float* __restrict__ alogb, const float* __restrict__ dvb,
    const ushortT* __restrict__ hin,
    ushortT* __restrict__ yf, ushortT* __restrict__ yb, int gB)
{
    int bid = blockIdx.x;
    int c = bid % NC_; bid /= NC_;
    int dchunk = bid % 3; bid /= 3;
    int b = bid % gB;
    int dir = bid / gB;
    int d = dchunk * 256 + threadIdx.x;

    const float* dbc  = dir ? dbcb : dbcf;
    const float* alog = dir ? alogb : alogf;
    float Dd          = (dir ? dvb : dvf)[d];
    ushortT* y        = dir ? yb : yf;

    float An[NS_];
#pragma unroll
    for (int n = 0; n < NS_; n++) An[n] = -__expf(alog[d * NS_ + n]);
    float a1 = An[0];
    bool pk = true;
#pragma unroll
    for (int n = 0; n < NS_; n++)
        pk = pk && (fabsf(An[n] - (float)(n + 1) * a1) <=
                    1e-3f * (float)(n + 1) * fabsf(a1) + 1e-6f);
    pk = (bool)__all((int)pk);

    __shared__ float sBC[LC_ * 32];
    int rb = b * LN_ + c * LC_;
    int jb = c * LC_;
#pragma unroll
    for (int i = 0; i < 2; i++) {
        int idx = threadIdx.x + 256 * i;
        int row = idx >> 3, c4 = (idx & 7) * 4;
        *(float4*)&sBC[row * 32 + c4] =
            *(const float4*)(dbc + (size_t)(rb + row) * NDBCP + RDT_ + c4);
    }
    __syncthreads();

    int si = (((dir * gB + b) * NC_ + c) * DI_ + d) * NS_;
    float h[NS_];
#pragma unroll
    for (int n = 0; n < NS_; n++) h[n] = bf2f(hin[si + n]);
    const uint32_t* udp = UD + (size_t)((dir * gB + b) * LN_ + jb) * DI_ + d;

    if (pk) {
        uint32_t ud8[8];
        ushortT z8[8];
#pragma unroll
        for (int i = 0; i < 8; i++) {
            ud8[i] = udp[i * DI_];
            int j = jb + i;
            int lo = dir ? (LN_ - 1 - j) : j;
            z8[i] = XZ[(size_t)(b * LN_ + lo) * (2 * DI_) + DI_ + d];
        }
        for (int lt = 0; lt < LC_; lt += 8) {
            uint32_t cud[8];
            ushortT cz[8];
#pragma unroll
            for (int i = 0; i < 8; i++) { cud[i] = ud8[i]; cz[i] = z8[i]; }
            if (lt + 8 < LC_) {
#pragma unroll
                for (int i = 0; i < 8; i++) {
                    ud8[i] = udp[(lt + 8 + i) * DI_];
                    int j = jb + lt + 8 + i;
                    int lo = dir ? (LN_ - 1 - j) : j;
                    z8[i] = XZ[(size_t)(b * LN_ + lo) * (2 * DI_) + DI_ + d];
                }
            }
#pragma unroll
            for (int i = 0; i < 8; i++) {
                int lr = lt + i;
                const float4* rp4 = (const float4*)&sBC[lr * 32];
                float4 B0 = rp4[0], B1 = rp4[1], B2 = rp4[2], B3 = rp4[3];
                float4 C0 = rp4[4], C1 = rp4[5], C2 = rp4[6], C3 = rp4[7];
                float Bv[NS_] = {B0.x, B0.y, B0.z, B0.w, B1.x, B1.y, B1.z, B1.w,
                                 B2.x, B2.y, B2.z, B2.w, B3.x, B3.y, B3.z, B3.w};
                float Cw[NS_] = {C0.x, C0.y, C0.z, C0.w, C1.x, C1.y, C1.z, C1.w,
                                 C2.x, C2.y, C2.z, C2.w, C3.x, C3.y, C3.z, C3.w};
                float u = bf2f((ushortT)(cud[i] & 0xffffu));
                float dt = bf2f((ushortT)(cud[i] >> 16));
                float du = dt * u;
                float q1 = __expf(dt * a1);
                float q2 = q1 * q1, q4 = q2 * q2, q8 = q4 * q4;
                float p2 = q2, p3 = q2 * q1, p5 = q4 * q1, p6 = q4 * q2, p7 = q4 * p3;
                float pw[NS_] = {q1, p2, p3, q4, p5, p6, p7, q8,
                                 q8 * q1, q8 * p2, q8 * p3, q8 * q4,
                                 q8 * p5, q8 * p6, q8 * p7, q8 * q8};
                float y0 = 0.f, y1 = 0.f, y2 = 0.f, y3 = 0.f;
#pragma unroll
                for (int n = 0; n < NS_; n += 4) {
                    h[n + 0] = fmaf(h[n + 0], pw[n + 0], du * Bv[n + 0]);
                    h[n + 1] = fmaf(h[n + 1], pw[n + 1], du * Bv[n + 1]);
                    h[n + 2] = fmaf(h[n + 2], pw[n + 2], du * Bv[n + 2]);
                    h[n + 3] = fmaf(h[n + 3], pw[n + 3], du * Bv[n + 3]);
                    y0 = fmaf(h[n + 0], Cw[n + 0], y0);
                    y1 = fmaf(h[n + 1], Cw[n + 1], y1);
                    y2 = fmaf(h[n + 2], Cw[n + 2], y2);
                    y3 = fmaf(h[n + 3], Cw[n + 3], y3);
                }
                float yv = ((y0 + y1) + (y2 + y3)) + u * Dd;
                int j = jb + lr;
                int lo = dir ? (LN_ - 1 - j) : j;
                float z = bf2f(cz[i]);
                y[(b * LN_ + lo) * DI_ + d] = f2bf(yv * silu_f(z));
            }
        }
    } else {
        for (int lr = 0; lr < LC_; lr++) {
            const float* rowp = &sBC[lr * 32];
            uint32_t ud = udp[lr * DI_];
            float u = bf2f((ushortT)(ud & 0xffffu));
            float dt = bf2f((ushortT)(ud >> 16));
            float du = dt * u;
            float y0 = 0.f, y1 = 0.f, y2 = 0.f, y3 = 0.f;
#pragma unroll
            for (int n = 0; n < NS_; n += 4) {
                h[n + 0] = fmaf(h[n + 0], __expf(dt * An[n + 0]), du * rowp[n + 0]);
                h[n + 1] = fmaf(h[n + 1], __expf(dt * An[n + 1]), du * rowp[n + 1]);
                h[n + 2] = fmaf(h[n + 2], __expf(dt * An[n + 2]), du * rowp[n + 2]);
                h[n + 3] = fmaf(h[n + 3], __expf(dt * An[n + 3]), du * rowp[n + 3]);
                y0 = fmaf(h[n + 0], rowp[16 + n + 0], y0);
                y1 = fmaf(h[n + 1], rowp[16 + n + 1], y1);
                y2 = fmaf(h[n + 2], rowp[16 + n + 2], y2);
                y3 = fmaf(h[n + 3], rowp[16 + n + 3], y3);
            }
            float yv = ((y0 + y1) + (y2 + y3)) + u * Dd;
            int j = jb + lr;
            int lo = dir ? (LN_ - 1 - j) : j;
            float z = bf2f(XZ[(size_t)(b * LN_ + lo) * (2 * DI_) + DI_ + d]);
            y[(b * LN_ + lo) * DI_ + d] = f2bf(yv * silu_f(z));
        }
    }
}

// ---------------------------------------------------------------------------
// Host launcher. Lifetime-aliased workspace plan so g=16 fits in 256 MiB:
//   region A: XNb (to gemm_in)        aliases SD  (from scan1)
//   region C: XH  (to dtud)          aliases Yf|Yb (from scan3)
// ---------------------------------------------------------------------------
extern "C" void kernel_launch(void* const* d_in, const int* in_sizes, int n_in,
                              void* d_out, int out_size, void* d_ws, size_t ws_size,
                              hipStream_t stream)
{
    const float* x         = (const float*)d_in[0];
    const float* ln_w      = (const float*)d_in[1];
    const float* ln_b      = (const float*)d_in[2];
    const float* in_proj_w = (const float*)d_in[3];
    const float* out_proj_w= (const float*)d_in[4];
    const float* conv_wf   = (const float*)d_in[5];
    const float* conv_bf   = (const float*)d_in[6];
    const float* xproj_f   = (const float*)d_in[7];
    const float* dt_wf     = (const float*)d_in[8];
    const float* dt_bf     = (const float*)d_in[9];
    const float* alog_f    = (const float*)d_in[10];
    const float* dv_f      = (const float*)d_in[11];
    const float* conv_wb   = (const float*)d_in[12];
    const float* conv_bb   = (const float*)d_in[13];
    const float* xproj_b   = (const float*)d_in[14];
    const float* dt_wb     = (const float*)d_in[15];
    const float* dt_bb     = (const float*)d_in[16];
    const float* alog_b    = (const float*)d_in[17];
    const float* dv_b      = (const float*)d_in[18];
    float* outp = (float*)d_out;

    const int n_w1 = 2 * DI_ * DM_;
    const int n_w2 = DM_ * DI_;
    const int n_wx = NDBCP * DI_;
    const int n_wd = DI_ * 32;

    auto al = [](size_t x) { return (x + 255) & ~(size_t)255; };
    size_t wbytes = al((size_t)n_w1 * 2) + al((size_t)n_w2 * 2) +
                    2 * al((size_t)n_wx * 2) + 2 * al((size_t)n_wd * 2);

    // choose largest g (power of 2 <= 16) whose aliased plan fits
    int g = BN_;
    while (g > 1) {
        size_t rows = (size_t)g * LN_;
        size_t st_n = (size_t)2 * g * NC_ * DI_ * NS_;
        size_t szA  = al((rows * DM_ * 2 > st_n * 4) ? rows * DM_ * 2 : st_n * 4);
        size_t need = wbytes + szA
                    + al(rows * 2 * DI_ * 2)        // XZ
                    + al(2 * rows * DI_ * 2)        // XH / Yf|Yb
                    + 2 * al(rows * NDBCP * 4)      // DBCf, DBCb
                    + al(2 * rows * 32 * 2)         // DT24
                    + al(2 * rows * DI_ * 4)        // UD
                    + al(st_n * 2);                 // HIN
        if (need <= ws_size) break;
        g >>= 1;
    }

    uint8_t* base = (uint8_t*)d_ws;
    size_t off = 0;
    auto alloc = [&](size_t nbytes) {
        uint8_t* r = base + off;
        off += al(nbytes);
        return r;
    };
    ushortT* WbIn  = (ushortT*)alloc((size_t)n_w1 * 2);
    ushortT* WbOut = (ushortT*)alloc((size_t)n_w2 * 2);
    ushortT* WbXf  = (ushortT*)alloc((size_t)n_wx * 2);
    ushortT* WbXb  = (ushortT*)alloc((size_t)n_wx * 2);
    ushortT* WbDtf = (ushortT*)alloc((size_t)n_wd * 2);
    ushortT* WbDtb = (ushortT*)alloc((size_t)n_wd * 2);

    wconv_kernel<<<(n_w1 + n_w2 + 2 * n_wx + 2 * n_wd + 255) / 256, 256, 0, stream>>>(
        in_proj_w, n_w1, out_proj_w, n_w2, xproj_f, xproj_b, dt_wf, dt_wb,
        WbIn, WbOut, WbXf, WbXb, WbDtf, WbDtb);

    {
        size_t rows = (size_t)g * LN_;
        size_t st_n = (size_t)2 * g * NC_ * DI_ * NS_;
        size_t szA  = al((rows * DM_ * 2 > st_n * 4) ? rows * DM_ * 2 : st_n * 4);

        uint8_t* regA = (uint8_t*)alloc(szA);            // XNb | SD
        ushortT* XZ   = (ushortT*)alloc(rows * 2 * DI_ * 2);
        uint8_t* regC = (uint8_t*)alloc(2 * rows * DI_ * 2);  // XH | Yf,Yb
        float* DBCf   = (float*)alloc(rows * NDBCP * 4);
        float* DBCb   = (float*)alloc(rows * NDBCP * 4);
        ushortT* DT24 = (ushortT*)alloc(2 * rows * 32 * 2);
        uint32_t* UD  = (uint32_t*)alloc(2 * rows * DI_ * 4);
        ushortT* HIN  = (ushortT*)alloc(st_n * 2);

        ushortT* XNb = (ushortT*)regA;
        uint32_t* SD = (uint32_t*)regA;
        ushortT* XH  = (ushortT*)regC;
        ushortT* Yf  = (ushortT*)regC;
        ushortT* Yb  = (ushortT*)(regC + rows * DI_ * 2);

        for (int b0 = 0; b0 < BN_; b0 += g) {
            int nrows = (int)rows;
            int row0 = b0 * LN_;

            ln_kernel<<<nrows / 4, 256, 0, stream>>>(x, ln_w, ln_b, XNb, row0, nrows);

            gemm_mfma<128, 128, 2, 2, false, false, true>
                <<<dim3(nrows / 128, (2 * DI_) / 128), 256, 0, stream>>>(
                XNb, nullptr, WbIn, nullptr, XZ, nrows, 2 * DI_, DM_);

            conv_kernel<<<(2 * nrows * (DI_ / 8)) / 256, 256, 0, stream>>>(
                XZ, conv_wf, conv_bf, conv_wb, conv_bb, XH, g);

            xproj_mfma<<<2 * (nrows / 64), 256, 0, stream>>>(
                XH, WbXf, WbXb, DBCf, DBCb, DT24, nrows / 64);

            dtud_kernel<<<dim3(nrows / 128, DI_ / 64, 2), 256, 0, stream>>>(
                DT24, WbDtf, WbDtb, dt_bf, dt_bb, XH, UD, nrows);

            scan1_kernel<<<2 * g * 3 * NC_, 256, 0, stream>>>(
                UD, DBCf, DBCb, alog_f, alog_b, SD, g);

            scan2_kernel<<<(2 * g * DI_ * NS_) / 256, 256, 0, stream>>>(SD, HIN, g);

            scan3_kernel<<<2 * g * 3 * NC_, 256, 0, stream>>>(
                UD, XZ, DBCf, DBCb, alog_f, dv_f, alog_b, dv_b,
                HIN, Yf, Yb, g);

            gemm_mfma<64, 128, 1, 4, true, true, false>
                <<<dim3(nrows / 64, DM_ / 128), 256, 0, stream>>>(
                Yf, Yb, WbOut, x + (size_t)row0 * DM_,
                outp + (size_t)row0 * DM_, nrows, DM_, DI_);
        }
    }
}